// Round 9
// baseline (571.399 us; speedup 1.0000x reference)
//
#include <hip/hip_runtime.h>
#include <cstdint>
#include <cstddef>

typedef _Float16 f16;
typedef _Float16 f16x4 __attribute__((ext_vector_type(4)));
typedef _Float16 f16x8 __attribute__((ext_vector_type(8)));
typedef float floatx4 __attribute__((ext_vector_type(4)));

#define MFMA32(a,b,c) __builtin_amdgcn_mfma_f32_16x16x32_f16((a),(b),(c),0,0,0)

#define ROWS 8192            // B*L
#define NCHUNK 128           // L/CS
#define NSUPER 64            // NCHUNK/2
// qkvgHi column order: k [0,512) | v [512,1536) | q [1536,2048) | g [2048,3072)
// After cabd_kernel, rows 0..1023 of the (dead) v-region hold the CAB/DBA
// coupling tables: row bh*64+sc, cols 512+[0,256)=CABh [256,512)=CABl
// [512,768)=DBAh [768,1024)=DBAl.
static constexpr float QSCALE = 0.08838834764831845f; // 128^-0.5

static __device__ __forceinline__ float sigmoidf_(float x) { return 1.0f / (1.0f + expf(-x)); }

static __device__ __forceinline__ uint32_t pack2(f16 a, f16 b) {
  union { f16 h[2]; uint32_t u; } v; v.h[0] = a; v.h[1] = b; return v.u;
}

// async global->LDS, 16B per lane; LDS dest is wave-uniform base (+lane*16 HW),
// global src is PER-LANE (pre-swizzled addressing lives here).
#define GLOAD_LDS(gptr, lptr)                                                  \
  __builtin_amdgcn_global_load_lds(                                            \
      (const __attribute__((address_space(1))) void*)(gptr),                   \
      (__attribute__((address_space(3))) void*)(lptr), 16, 0, 0)

// counted vmcnt wait (never drain to 0 in steady state) + scheduler fence
#define WAITV(N) do { asm volatile("s_waitcnt vmcnt(" #N ")" ::: "memory");    \
                      __builtin_amdgcn_sched_barrier(0); } while (0)

#define SBAR() __builtin_amdgcn_sched_barrier(0)

// ---------------------------------------------------------------------------
// 1) Weights -> f16. Wcat rows: [0,512)=Wk [512,1536)=Wv [1536,2048)=Wq
//    [2048,3072)=Wg. hi all; lo only k,v rows. Wo -> hi only.
// ---------------------------------------------------------------------------
__global__ __launch_bounds__(256) void wconv_kernel(
    const float* __restrict__ Wq, const float* __restrict__ Wk,
    const float* __restrict__ Wv, const float* __restrict__ Wg,
    const float* __restrict__ Wo,
    f16* __restrict__ WcatHi, f16* __restrict__ WcatLoKV, f16* __restrict__ WoHi) {
  int tid = blockIdx.x * 256 + threadIdx.x;
  int e8 = tid * 8;
  if (e8 < 3145728) {
    int row = e8 >> 10, col = e8 & 1023;
    const float* src;
    if (row < 512)       src = Wk + (size_t)row * 1024 + col;
    else if (row < 1536) src = Wv + (size_t)(row - 512) * 1024 + col;
    else if (row < 2048) src = Wq + (size_t)(row - 1536) * 1024 + col;
    else                 src = Wg + (size_t)(row - 2048) * 1024 + col;
    f16 thi[8] __attribute__((aligned(16)));
    f16 tlo[8] __attribute__((aligned(16)));
#pragma unroll
    for (int j = 0; j < 8; j++) {
      float x = src[j];
      f16 h = (f16)x;
      thi[j] = h;
      tlo[j] = (f16)(x - (float)h);
    }
    *(uint4*)&WcatHi[e8] = *(const uint4*)thi;
    if (row < 1536) *(uint4*)&WcatLoKV[e8] = *(const uint4*)tlo;
  } else {
    int idx = e8 - 3145728;
    f16 t[8] __attribute__((aligned(16)));
#pragma unroll
    for (int j = 0; j < 8; j++) t[j] = (f16)Wo[idx + j];
    *(uint4*)&WoHi[idx] = *(const uint4*)t;
  }
}

// ---------------------------------------------------------------------------
// 2) Causal depthwise conv1d (K=4) + SiLU -> x hi/lo
// ---------------------------------------------------------------------------
__global__ __launch_bounds__(256) void conv_kernel(
    const float* __restrict__ hs, const float* __restrict__ cw,
    f16* __restrict__ xhi, f16* __restrict__ xlo) {
  int row = blockIdx.x;
  int b = row >> 11, l = row & 2047;
  int d = threadIdx.x * 4;
  floatx4 w0 = *(const floatx4*)&cw[(d + 0) * 4];
  floatx4 w1 = *(const floatx4*)&cw[(d + 1) * 4];
  floatx4 w2 = *(const floatx4*)&cw[(d + 2) * 4];
  floatx4 w3 = *(const floatx4*)&cw[(d + 3) * 4];
  floatx4 acc = {0.f, 0.f, 0.f, 0.f};
#pragma unroll
  for (int j = 0; j < 4; j++) {
    int ls = l - 3 + j;
    if (ls < 0) continue;
    floatx4 hv = *(const floatx4*)&hs[(size_t)(b * 2048 + ls) * 1024 + d];
    acc[0] += hv[0] * w0[j];
    acc[1] += hv[1] * w1[j];
    acc[2] += hv[2] * w2[j];
    acc[3] += hv[3] * w3[j];
  }
  f16 ohi[4] __attribute__((aligned(8)));
  f16 olo[4] __attribute__((aligned(8)));
#pragma unroll
  for (int q = 0; q < 4; q++) {
    float y = acc[q] * sigmoidf_(acc[q]);
    f16 h = (f16)y;
    ohi[q] = h;
    olo[q] = (f16)(y - (float)h);
  }
  *(uint2*)&xhi[(size_t)row * 1024 + d] = *(const uint2*)ohi;
  *(uint2*)&xlo[(size_t)row * 1024 + d] = *(const uint2*)olo;
}

// ---------------------------------------------------------------------------
// 3) beta[row][h] = sigmoid(x . Wb[h])
// ---------------------------------------------------------------------------
__global__ __launch_bounds__(256) void beta_kernel(
    const f16* __restrict__ xhi, const f16* __restrict__ xlo,
    const float* __restrict__ Wb, float* __restrict__ betaf) {
  int row = blockIdx.x;
  int t = threadIdx.x;
  __shared__ floatx4 red[256];
  int c = t * 4;
  float xv[4];
#pragma unroll
  for (int j = 0; j < 4; j++)
    xv[j] = (float)xhi[(size_t)row * 1024 + c + j] + (float)xlo[(size_t)row * 1024 + c + j];
  floatx4 p = {0.f, 0.f, 0.f, 0.f};
#pragma unroll
  for (int hh = 0; hh < 4; hh++) {
    const float* wr = Wb + hh * 1024 + c;
    p[hh] = xv[0] * wr[0] + xv[1] * wr[1] + xv[2] * wr[2] + xv[3] * wr[3];
  }
  red[t] = p;
  __syncthreads();
  for (int s = 128; s > 0; s >>= 1) {
    if (t < s) red[t] += red[t + s];
    __syncthreads();
  }
  if (t < 4) betaf[(size_t)row * 4 + t] = sigmoidf_(red[0][t]);
}

// ---------------------------------------------------------------------------
// 4) MERGED x-projection GEMM, grid (24, 64).
//    blockIdx.x <  12: hi/lo path for k,v cols (3 MFMAs/tile, ChHi+ChLo)
//    blockIdx.x >= 12: plain path for q,g cols (1 MFMA/tile, ChHi only)
//    The two former kernels were independent (disjoint output columns);
//    merging halves the dispatch tails and drops one launch.
// ---------------------------------------------------------------------------
__global__ __launch_bounds__(256) void gemm_qkvg(
    const f16* __restrict__ Ahi, const f16* __restrict__ Alo,
    const f16* __restrict__ Bhi, const f16* __restrict__ Blo,
    f16* __restrict__ ChHi, f16* __restrict__ ChLo) {
  const int K = 1024;
  __shared__ __attribute__((aligned(16))) f16 AsH[4096];
  __shared__ __attribute__((aligned(16))) f16 AsL[4096];
  __shared__ __attribute__((aligned(16))) f16 BsH[4096];
  __shared__ __attribute__((aligned(16))) f16 BsL[4096];
  const int t = threadIdx.x;
  const int lane = t & 63, wave = t >> 6;
  const int lc = lane & 15, quad = lane >> 4;
  const int wm = (wave >> 1) * 64, wn = (wave & 1) * 64;
  const int m0 = blockIdx.y * 128, n0 = blockIdx.x * 128;
  const bool hilo = (blockIdx.x < 12);     // k,v cols carry lo corrections
  const int scol = ((lane & 3) ^ ((lane >> 3) & 3)) * 8;
  int srow[2];
#pragma unroll
  for (int pp = 0; pp < 2; pp++) srow[pp] = (wave * 2 + pp) * 16 + (lane >> 2);
  const int swz = (quad ^ ((lc >> 1) & 3)) * 8;
  floatx4 acc[4][4] = {};
  for (int kt = 0; kt < K; kt += 32) {
    __syncthreads();
#pragma unroll
    for (int pp = 0; pp < 2; pp++) {
      int ldso = (wave * 2 + pp) * 512;
      GLOAD_LDS(&Ahi[(size_t)(m0 + srow[pp]) * K + kt + scol], AsH + ldso);
      GLOAD_LDS(&Bhi[(size_t)(n0 + srow[pp]) * K + kt + scol], BsH + ldso);
      if (hilo) {
        GLOAD_LDS(&Alo[(size_t)(m0 + srow[pp]) * K + kt + scol], AsL + ldso);
        GLOAD_LDS(&Blo[(size_t)(n0 + srow[pp]) * K + kt + scol], BsL + ldso);
      }
    }
    __syncthreads();    // drains vmcnt(0) -> staged data visible
    f16x8 ah[4], bh2[4];
#pragma unroll
    for (int i = 0; i < 4; i++) ah[i] = *(const f16x8*)&AsH[(wm + i * 16 + lc) * 32 + swz];
#pragma unroll
    for (int j = 0; j < 4; j++) bh2[j] = *(const f16x8*)&BsH[(wn + j * 16 + lc) * 32 + swz];
    if (hilo) {
      f16x8 al[4], bl[4];
#pragma unroll
      for (int i = 0; i < 4; i++) al[i] = *(const f16x8*)&AsL[(wm + i * 16 + lc) * 32 + swz];
#pragma unroll
      for (int j = 0; j < 4; j++) bl[j] = *(const f16x8*)&BsL[(wn + j * 16 + lc) * 32 + swz];
#pragma unroll
      for (int i = 0; i < 4; i++)
#pragma unroll
        for (int j = 0; j < 4; j++) {
          acc[i][j] = MFMA32(ah[i], bh2[j], acc[i][j]);
          acc[i][j] = MFMA32(al[i], bh2[j], acc[i][j]);
          acc[i][j] = MFMA32(ah[i], bl[j], acc[i][j]);
        }
    } else {
#pragma unroll
      for (int i = 0; i < 4; i++)
#pragma unroll
        for (int j = 0; j < 4; j++) acc[i][j] = MFMA32(ah[i], bh2[j], acc[i][j]);
    }
  }
#pragma unroll
  for (int i = 0; i < 4; i++)
#pragma unroll
    for (int j = 0; j < 4; j++)
#pragma unroll
      for (int rr = 0; rr < 4; rr++) {
        int row = m0 + wm + i * 16 + quad * 4 + rr;
        int col = n0 + wn + j * 16 + lc;
        float x = acc[i][j][rr];
        f16 h = (f16)x;
        ChHi[(size_t)row * 3072 + col] = h;
        if (hilo) ChLo[(size_t)row * 1536 + col] = (f16)(x - (float)h);
      }
}

// ---------------------------------------------------------------------------
// 4b) Plain f16 GEMM (global_load_lds staging) — used only for the output
//     projection (OUTF16=0).
// ---------------------------------------------------------------------------
template <int OUTF16>
__global__ __launch_bounds__(256) void gemm_plain(
    const f16* __restrict__ A, const f16* __restrict__ Bw,
    f16* __restrict__ Ch, float* __restrict__ Cf, int K, int ldc) {
  __shared__ __attribute__((aligned(16))) f16 As[4096];
  __shared__ __attribute__((aligned(16))) f16 Bs[4096];
  const int t = threadIdx.x;
  const int lane = t & 63, wave = t >> 6;
  const int lc = lane & 15, quad = lane >> 4;
  const int wm = (wave >> 1) * 64, wn = (wave & 1) * 64;
  const int m0 = blockIdx.y * 128, n0 = blockIdx.x * 128;
  const int scol = ((lane & 3) ^ ((lane >> 3) & 3)) * 8;
  int srow[2];
#pragma unroll
  for (int pp = 0; pp < 2; pp++) srow[pp] = (wave * 2 + pp) * 16 + (lane >> 2);
  const int swz = (quad ^ ((lc >> 1) & 3)) * 8;
  floatx4 acc[4][4] = {};
  for (int kt = 0; kt < K; kt += 32) {
    __syncthreads();
#pragma unroll
    for (int pp = 0; pp < 2; pp++) {
      int ldso = (wave * 2 + pp) * 512;
      GLOAD_LDS(&A[(size_t)(m0 + srow[pp]) * K + kt + scol],  As + ldso);
      GLOAD_LDS(&Bw[(size_t)(n0 + srow[pp]) * K + kt + scol], Bs + ldso);
    }
    __syncthreads();
    f16x8 af[4], bf[4];
#pragma unroll
    for (int i = 0; i < 4; i++) af[i] = *(const f16x8*)&As[(wm + i * 16 + lc) * 32 + swz];
#pragma unroll
    for (int j = 0; j < 4; j++) bf[j] = *(const f16x8*)&Bs[(wn + j * 16 + lc) * 32 + swz];
#pragma unroll
    for (int i = 0; i < 4; i++)
#pragma unroll
      for (int j = 0; j < 4; j++) acc[i][j] = MFMA32(af[i], bf[j], acc[i][j]);
  }
#pragma unroll
  for (int i = 0; i < 4; i++)
#pragma unroll
    for (int j = 0; j < 4; j++)
#pragma unroll
      for (int rr = 0; rr < 4; rr++) {
        int row = m0 + wm + i * 16 + quad * 4 + rr;
        int col = n0 + wn + j * 16 + lc;
        if (OUTF16) Ch[(size_t)row * ldc + col] = (f16)acc[i][j][rr];
        else        Cf[(size_t)row * ldc + col] = acc[i][j][rr];
      }
}

// ---------------------------------------------------------------------------
// 5) Chunk pre-pass (unchanged).
// ---------------------------------------------------------------------------
__global__ __launch_bounds__(256) void prepass_kernel(
    const f16* __restrict__ qkvgHi, const f16* __restrict__ kvLo,
    const float* __restrict__ betaf,
    f16* __restrict__ wHi, f16* __restrict__ wLo,
    f16* __restrict__ kTHi, f16* __restrict__ kTLo,
    f16* __restrict__ uHi, f16* __restrict__ uLo,
    float* __restrict__ attno) {
  int bid = blockIdx.x;          // 16*128
  int bh = bid >> 7, n = bid & 127;
  int b = bh >> 2, h = bh & 3;
  int t = threadIdx.x;

  __shared__ __attribute__((aligned(16))) float kc[16][132];
  __shared__ __attribute__((aligned(16))) float qc[16][132];
  __shared__ __attribute__((aligned(16))) float vb[16][260];
  __shared__ float Mm[16][16];
  __shared__ float Tt[16][16];
  __shared__ float Tb[16][16];
  __shared__ float part[16][16];
  __shared__ float betas[16];
  __shared__ float nrm[16];

  const size_t rowbase = (size_t)(b * 2048 + n * 16);
  {
    int i = t >> 4, o8 = (t & 15) * 8;
    size_t oh = (rowbase + i) * 3072;
    size_t ol = (rowbase + i) * 1536;
#pragma unroll
    for (int j = 0; j < 8; j++)
      kc[i][o8 + j] = (float)qkvgHi[oh + h * 128 + o8 + j] +
                      (float)kvLo[ol + h * 128 + o8 + j];
#pragma unroll
    for (int j = 0; j < 8; j++)
      qc[i][o8 + j] = (float)qkvgHi[oh + 1536 + h * 128 + o8 + j];
  }
  if (t < 16) betas[t] = betaf[(rowbase + t) * 4 + h];
  __syncthreads();
  {
    int i = t >> 4, sg = t & 15;
    float s = 0.f;
#pragma unroll
    for (int j = 0; j < 8; j++) { float v = kc[i][sg * 8 + j]; s += v * v; }
    part[i][sg] = s;
  }
  __syncthreads();
  if (t < 16) {
    float s = 0.f;
#pragma unroll
    for (int j = 0; j < 16; j++) s += part[t][j];
    nrm[t] = rsqrtf(s + 1e-12f);
  }
  __syncthreads();
  {
    int i = t >> 4, o8 = (t & 15) * 8;
    float sc = nrm[i];
#pragma unroll
    for (int j = 0; j < 8; j++) kc[i][o8 + j] *= sc;
  }
  __syncthreads();
  { // kT: normalized k transposed [d][token], hi/lo
    int d = t & 127, ih = t >> 7;
    f16 thi[8] __attribute__((aligned(16)));
    f16 tlo[8] __attribute__((aligned(16)));
#pragma unroll
    for (int j = 0; j < 8; j++) {
      float x = kc[ih * 8 + j][d];
      f16 hh = (f16)x;
      thi[j] = hh;
      tlo[j] = (f16)(x - (float)hh);
    }
    size_t base = ((size_t)bh * 128 + n) * 2048 + d * 16 + ih * 8;
    *(uint4*)&kTHi[base] = *(const uint4*)thi;
    *(uint4*)&kTLo[base] = *(const uint4*)tlo;
  }
  { // M = I + beta_i * (k_i . k_j) strictly-lower
    int i = t >> 4, j = t & 15;
    float s = 0.f;
    for (int x = 0; x < 128; x += 4)
      s += kc[i][x] * kc[j][x] + kc[i][x + 1] * kc[j][x + 1] +
           kc[i][x + 2] * kc[j][x + 2] + kc[i][x + 3] * kc[j][x + 3];
    Mm[i][j] = (i == j ? 1.f : 0.f) + ((j < i) ? betas[i] * s : 0.f);
  }
  __syncthreads();
  if (t < 16) { // forward substitution, column t of T = M^-1
    int j = t;
    float Tc[16];
#pragma unroll
    for (int i = 0; i < 16; i++) Tc[i] = 0.f;
    Tc[j] = 1.f;
    for (int i = j + 1; i < 16; i++) {
      float s = 0.f;
      for (int k2 = j; k2 < i; k2++) s += Mm[i][k2] * Tc[k2];
      Tc[i] = -s;
    }
    for (int i = 0; i < 16; i++) Tt[i][j] = Tc[i];
  }
  __syncthreads();
  { int i = t >> 4, m = t & 15; Tb[i][m] = Tt[i][m] * betas[m]; }
  { // vb = v * beta
    int m = t >> 4, c16 = (t & 15) * 16;
    size_t oh = (rowbase + m) * 3072 + 512 + h * 256 + c16;
    size_t ol = (rowbase + m) * 1536 + 512 + h * 256 + c16;
    float bm = betas[m];
#pragma unroll
    for (int j = 0; j < 16; j++)
      vb[m][c16 + j] = bm * ((float)qkvgHi[oh + j] + (float)kvLo[ol + j]);
  }
  __syncthreads();
  { // -w = -(Tb @ k_norm), hi/lo
    int i = t >> 4, dg = t & 15;
    f16 thi[8] __attribute__((aligned(16)));
    f16 tlo[8] __attribute__((aligned(16)));
#pragma unroll
    for (int dd = 0; dd < 8; dd++) {
      int d = dg * 8 + dd;
      float s = 0.f;
#pragma unroll
      for (int m = 0; m < 16; m++) s += Tb[i][m] * kc[m][d];
      s = -s;
      f16 hh = (f16)s;
      thi[dd] = hh;
      tlo[dd] = (f16)(s - (float)hh);
    }
    size_t base = ((size_t)bh * 128 + n) * 2048 + i * 128 + dg * 8;
    *(uint4*)&wHi[base] = *(const uint4*)thi;
    *(uint4*)&wLo[base] = *(const uint4*)tlo;
  }
  { // u = Tt @ vb, hi/lo, chunk-TRANSPOSED out: [vg][bh][n][vv][i]
    int v = t;
    f16 thi[16] __attribute__((aligned(16)));
    f16 tlo[16] __attribute__((aligned(16)));
#pragma unroll
    for (int i = 0; i < 16; i++) {
      float s2 = 0.f;
#pragma unroll
      for (int m = 0; m < 16; m++) s2 += Tt[i][m] * vb[m][v];
      f16 hh = (f16)s2;
      thi[i] = hh;
      tlo[i] = (f16)(s2 - (float)hh);
    }
    size_t base = ((((size_t)(v >> 4) * 16 + bh) * 128 + n) * 16 + (v & 15)) * 16;
    ((uint4*)&uHi[base])[0] = ((const uint4*)thi)[0];
    ((uint4*)&uHi[base])[1] = ((const uint4*)thi)[1];
    ((uint4*)&uLo[base])[0] = ((const uint4*)tlo)[0];
    ((uint4*)&uLo[base])[1] = ((const uint4*)tlo)[1];
  }
  { // attn = qscale * (q . k_norm), causal inclusive, fp32
    int i = t >> 4, j = t & 15;
    float s = 0.f;
    for (int x = 0; x < 128; x++) s += qc[i][x] * kc[j][x];
    attno[((size_t)bh * 128 + n) * 256 + i * 16 + j] = (j <= i) ? QSCALE * s : 0.f;
  }
}

// ---------------------------------------------------------------------------
// 5b) Pair-coupling pre-pass (unchanged): CAB = (-wB)@kTA, DBA = qB@kTA,
//     stored in qkvgHi's dead v-region (row bh*64+sc, col 512+...).
// ---------------------------------------------------------------------------
__global__ __launch_bounds__(256) void cabd_kernel(
    f16* qkvg,
    const f16* __restrict__ wHi, const f16* __restrict__ wLo,
    const f16* __restrict__ kTHi, const f16* __restrict__ kTLo) {
  int bid = blockIdx.x;            // 16*64
  int bh = bid >> 6, sc = bid & 63;
  int b = bh >> 2, h = bh & 3;
  int t = threadIdx.x;
  int cA = 2 * sc, cB = 2 * sc + 1;
  const size_t cb = (size_t)bh * 128;

  __shared__ float wf[16][128];
  __shared__ float qf[16][128];
  __shared__ float kf[128][17];

  {
    int i = t >> 4, d0 = (t & 15) * 8;
    size_t wbase = (cb + cB) * 2048 + i * 128 + d0;
    size_t qbase = ((size_t)b * 2048 + cB * 16 + i) * 3072 + 1536 + h * 128 + d0;
#pragma unroll
    for (int j = 0; j < 8; j++) {
      wf[i][d0 + j] = (float)wHi[wbase + j] + (float)wLo[wbase + j];
      qf[i][d0 + j] = (float)qkvg[qbase + j];
    }
    int d = t >> 1, tk0 = (t & 1) * 8;
    size_t kb = (cb + cA) * 2048 + d * 16 + tk0;
#pragma unroll
    for (int j = 0; j < 8; j++)
      kf[d][tk0 + j] = (float)kTHi[kb + j] + (float)kTLo[kb + j];
  }
  __syncthreads();
  int i = t >> 4, j = t & 15;
  float sc1 = 0.f, sd1 = 0.f;
  for (int d = 0; d < 128; d++) {
    float kv = kf[d][j];
    sc1 += wf[i][d] * kv;
    sd1 += qf[i][d] * kv;
  }
  f16 ch = (f16)sc1, dh = (f16)sd1;
  size_t o = (size_t)(bh * 64 + sc) * 3072 + 512 + i * 16 + j;
  qkvg[o]       = ch;  qkvg[o + 256] = (f16)(sc1 - (float)ch);
  qkvg[o + 512] = dh;  qkvg[o + 768] = (f16)(sd1 - (float)dh);
}

// ---------------------------------------------------------------------------
// 6) Delta-rule scan, SUPERCHUNK-2 — ROUND-7 body verbatim (measured best,
//    177.8 us).  Round-8's deferred stores regressed (-18 us): extending the
//    acc_o live range across the accS block hurt more than any store-ack
//    slack helped.  Stores live at the o-finish (steps 14/15).
//    vmcnt ledger (groups fenced): B16 U4 W16 stA4 stB4 K16 = 60/body.
//      top WAITV(16); mid WAITV(44) (sc==63: 24); peaks <= 60 <= 63.
// ---------------------------------------------------------------------------
#define STG_W   0
#define STG_WL  2048
#define STG_KH  4096
#define STG_KL  6144
#define STG_CH  8192     // f16 per chunk buffer (16KB)

__global__ __launch_bounds__(64, 1) void scan_kernel(
    const f16* __restrict__ qkvgHi,
    const f16* __restrict__ wHi, const f16* __restrict__ wLo,
    const f16* __restrict__ kTHi, const f16* __restrict__ kTLo,
    const float* __restrict__ attn,
    const f16* __restrict__ uHi, const f16* __restrict__ uLo,
    float* __restrict__ o1, float* __restrict__ o2) {
  const int bid = blockIdx.x;
  const int slc = bid >> 4, bh = bid & 15;   // XCD-local: bid%8 = bh%8
  const int b = bh >> 2, h = bh & 3;
  const int v0 = slc * 16;
  const int lane = threadIdx.x;
  const int lc = lane & 15, quad = lane >> 4;
  const int qh = quad & 1;

  __shared__ __attribute__((aligned(16))) f16 stg[2][STG_CH];  // [chunk-in-pair]
  __shared__ __attribute__((aligned(16))) f16 S_hi[16][136];
  __shared__ __attribute__((aligned(16))) f16 S_lo[16][136];

  floatx4 accS[8] = {};   // S[dt*16 + quad*4 + r][v0 + lc]

  const size_t cb = (size_t)bh * 128;
  const f16* qb = qkvgHi + (size_t)b * 2048 * 3072 + 1536 + h * 128;
  const f16* ubH = uHi + ((size_t)(slc * 16 + bh)) * 32768 + lc * 16 + quad * 4;
  const f16* ubL = uLo + ((size_t)(slc * 16 + bh)) * 32768 + lc * 16 + quad * 4;
  const float* ab = attn + cb * 256 + lc * 16 + qh * 8;
  // CAB/DBA tables in qkvgHi v-region: row bh*64+sc, col 512+...
  const f16* cd = qkvgHi + (size_t)(bh * 64) * 3072 + 512 + lc * 16 + qh * 8;
  float* ob = (bh < 12) ? (o1 + (size_t)bh * 2048 * 256)
                        : (o2 + (size_t)(bh - 12) * 2048 * 256);

  // per-lane swizzled source offsets (chunk-invariant)
  int woff[4], koff[4];
#pragma unroll
  for (int p = 0; p < 4; p++) {
    int cid = p * 64 + lane;
    int row = cid >> 4, dgs = (cid & 15) ^ (row & 7);
    int d = cid >> 1,  ih = (cid & 1) ^ ((cid >> 3) & 1);
    woff[p] = row * 128 + dgs * 8;
    koff[p] = d * 16 + ih * 8;
  }

  // u prefetch, 2 slots (the only cross-body register prefetch)
  uint2 puhA[2], pulA[2], puhB[2], pulB[2];

  auto ISSUE_U = [&](int slot, int sc) {   // 4 VMEM
    puhA[slot] = *(const uint2*)(ubH + (size_t)(2 * sc) * 256);
    pulA[slot] = *(const uint2*)(ubL + (size_t)(2 * sc) * 256);
    puhB[slot] = *(const uint2*)(ubH + (size_t)(2 * sc + 1) * 256);
    pulB[slot] = *(const uint2*)(ubL + (size_t)(2 * sc + 1) * 256);
  };
  auto ISSUE_W = [&](int sc) {   // 16 gloads (both chunks)
#pragma unroll
    for (int ci = 0; ci < 2; ci++) {
      const f16* ws = wHi + (cb + (size_t)(2 * sc + ci)) * 2048;
      const f16* wl = wLo + (cb + (size_t)(2 * sc + ci)) * 2048;
      f16* sbp = &stg[ci][0];
#pragma unroll
      for (int p = 0; p < 4; p++) {
        GLOAD_LDS(ws + woff[p], sbp + STG_W  + p * 512);
        GLOAD_LDS(wl + woff[p], sbp + STG_WL + p * 512);
      }
    }
  };
  auto ISSUE_K = [&](int sc) {   // 16 gloads (both chunks)
#pragma unroll
    for (int ci = 0; ci < 2; ci++) {
      const f16* kh = kTHi + (cb + (size_t)(2 * sc + ci)) * 2048;
      const f16* kl = kTLo + (cb + (size_t)(2 * sc + ci)) * 2048;
      f16* sbp = &stg[ci][0];
#pragma unroll
      for (int p = 0; p < 4; p++) {
        GLOAD_LDS(kh + koff[p], sbp + STG_KH + p * 512);
        GLOAD_LDS(kl + koff[p], sbp + STG_KL + p * 512);
      }
    }
  };

  auto SHFL_EXCH = [&](floatx4 acc_u) -> f16x8 {
    f16 h0 = (f16)acc_u[0], h1 = (f16)acc_u[1];
    f16 h2 = (f16)acc_u[2], h3 = (f16)acc_u[3];
    uint32_t uh01 = pack2(h0, h1), uh23 = pack2(h2, h3);
    uint32_t ul01 = pack2((f16)(acc_u[0] - (float)h0), (f16)(acc_u[1] - (float)h1));
    uint32_t ul23 = pack2((f16)(acc_u[2] - (float)h2), (f16)(acc_u[3] - (float)h3));
    int srcA = (2 * qh) * 16 + lc;
    int srcB = srcA + 16;
    uint32_t Ah0 = __shfl((int)uh01, srcA, 64), Ah1 = __shfl((int)uh23, srcA, 64);
    uint32_t Bh0 = __shfl((int)uh01, srcB, 64), Bh1 = __shfl((int)uh23, srcB, 64);
    uint32_t Al0 = __shfl((int)ul01, srcA, 64), Al1 = __shfl((int)ul23, srcA, 64);
    uint32_t Bl0 = __shfl((int)ul01, srcB, 64), Bl1 = __shfl((int)ul23, srcB, 64);
    union { uint32_t u[4]; f16x8 v; } U;
    bool hi = (quad < 2);
    U.u[0] = hi ? Ah0 : Al0;
    U.u[1] = hi ? Ah1 : Al1;
    U.u[2] = hi ? Bh0 : Bl0;
    U.u[3] = hi ? Bh1 : Bl1;
    return U.v;
  };

  // attn fp32x8 -> hi/lo f16x8 frags
  auto ATTN_SPLIT = [&](uint4 p0, uint4 p1, f16x8& hh, f16x8& ll) {
    union { uint4 u4[2]; float f[8]; } PA;
    PA.u4[0] = p0; PA.u4[1] = p1;
#pragma unroll
    for (int j = 0; j < 8; j++) {
      float a = PA.f[j];
      f16 ah = (f16)a;
      hh[j] = ah;
      ll[j] = (f16)(a - (float)ah);
    }
  };

  const int kswz = (qh ^ ((lc >> 2) & 1)) * 8 + lc * 16;

  // prologue: superchunk 0 fully in flight (U4 + W16 + K16 = 36)
  ISSUE_U(0, 0); SBAR();
  ISSUE_W(0);    SBAR();
  ISSUE_K(0);    SBAR();

  for (int s2 = 0; s2 < NSUPER; s2 += 2) {
#pragma unroll
    for (int half = 0; half < 2; half++) {
      const int sc = s2 + half;
      const int slot = half;           // = sc & 1
      const int cA = 2 * sc;

      // ---- 1. dump S (state after superchunk sc-1) hi/lo to LDS
#pragma unroll
      for (int dt = 0; dt < 8; dt++) {
        f16x4 h4, l4;
#pragma unroll
        for (int r = 0; r < 4; r++) {
          float x = accS[dt][r];
          f16 hh = (f16)x;
          h4[r] = hh;
          l4[r] = (f16)(x - (float)hh);
        }
        *(f16x4*)&S_hi[lc][dt * 16 + quad * 4] = h4;
        *(f16x4*)&S_lo[lc][dt * 16 + quad * 4] = l4;
      }

      // ---- 2. top wait: W(sc)+U(sc) staged (16 = K(sc) left outstanding)
      WAITV(16);

      // ---- 3. same-body register loads: attn, CAB/DBA, q (B group, 16)
      uint4 paA0 = *(const uint4*)(ab + (size_t)cA * 256);
      uint4 paA1 = *(const uint4*)(ab + (size_t)cA * 256 + 4);
      uint4 paB0 = *(const uint4*)(ab + (size_t)(cA + 1) * 256);
      uint4 paB1 = *(const uint4*)(ab + (size_t)(cA + 1) * 256 + 4);
      const f16* cdp = cd + (size_t)sc * 3072;
      f16x8 cabh = *(const f16x8*)(cdp);
      f16x8 cabl = *(const f16x8*)(cdp + 256);
      f16x8 dbah = *(const f16x8*)(cdp + 512);
      f16x8 dbal = *(const f16x8*)(cdp + 768);
      f16x8 qfA[4], qfB[4];
#pragma unroll
      for (int ks = 0; ks < 4; ks++) {
        qfA[ks] = *(const f16x8*)(qb + (size_t)(cA * 16 + lc) * 3072 + ks * 32 + quad * 8);
        qfB[ks] = *(const f16x8*)(qb + (size_t)((cA + 1) * 16 + lc) * 3072 + ks * 32 + quad * 8);
      }
      SBAR();

      // ---- 4. consume u prefetch
      floatx4 acc_uA, acc_uB;
      {
        union { uint2 u2; f16 hh[4]; } Uh, Ul;
        Uh.u2 = puhA[slot]; Ul.u2 = pulA[slot];
#pragma unroll
        for (int r = 0; r < 4; r++) acc_uA[r] = (float)Uh.hh[r] + (float)Ul.hh[r];
        Uh.u2 = puhB[slot]; Ul.u2 = pulB[slot];
#pragma unroll
        for (int r = 0; r < 4; r++) acc_uB[r] = (float)Uh.hh[r] + (float)Ul.hh[r];
      }
      // ---- 5. next-superchunk u prefetch (U group, 4)
      if (sc + 1 < NSUPER) ISSUE_U(slot ^ 1, sc + 1);
      SBAR();

      // ---- 6. S frags + wA frags
      f16x8 shf[4], slf[4], wah[4], wal[4];
      f16* sbA = &stg[0][0];
      f16* sbB = &stg[1][0];
#pragma unroll
      for (int ks = 0; ks < 4; ks++) {
        shf[ks] = *(const f16x8*)&S_hi[lc][ks * 32 + quad * 8];
        slf[ks] = *(const f16x8*)&S_lo[lc][ks * 32 + quad * 8];
        int gi = lc * 128 + (((ks * 4 + quad) ^ (lc & 7)) * 8);
        wah[ks] = *(const f16x8*)(sbA + STG_W  + gi);
        wal[ks] = *(const f16x8*)(sbA + STG_WL + gi);
      }
      // ---- 7. yA trio (bit-identical A path)
      floatx4 a1 = {0.f,0.f,0.f,0.f}, a2 = {0.f,0.f,0.f,0.f};
#pragma unroll
      for (int ks = 0; ks < 4; ks++) {
        acc_uA = MFMA32(wah[ks], shf[ks], acc_uA);
        a1     = MFMA32(wah[ks], slf[ks], a1);
        a2     = MFMA32(wal[ks], shf[ks], a2);
      }
      acc_uA = acc_uA + a1 + a2;

      // ---- 8. wB frags
      f16x8 wbh[4], wbl[4];
#pragma unroll
      for (int ks = 0; ks < 4; ks++) {
        int gi = lc * 128 + (((ks * 4 + quad) ^ (lc & 7)) * 8);
        wbh[ks] = *(const f16x8*)(sbB + STG_W  + gi);
        wbl[ks] = *(const f16x8*)(sbB + STG_WL + gi);
      }
      // ---- 9. yB trio
      floatx4 b1 = {0.f,0.f,0.f,0.f}, b2 = {0.f,0.f,0.f,0.f};
#pragma unroll
      for (int ks = 0; ks < 4; ks++) {
        acc_uB = MFMA32(wbh[ks], shf[ks], acc_uB);
        b1     = MFMA32(wbh[ks], slf[ks], b1);
        b2     = MFMA32(wbl[ks], shf[ks], b2);
      }
      acc_uB = acc_uB + b1 + b2;
      SBAR();
      // ---- 10. W staging for sc+1 (w frag reads retired above) (W group, 16)
      if (sc + 1 < NSUPER) ISSUE_W(sc + 1);
      SBAR();

      // ---- 11. oA' = qA@S, oB' = qB@S (parallel filler)
      floatx4 acc_oA = {0.f,0.f,0.f,0.f}, acc_oB = {0.f,0.f,0.f,0.f};
#pragma unroll
      for (int ks = 0; ks < 4; ks++) {
        acc_oA = MFMA32(qfA[ks], shf[ks], acc_oA);
        acc_oB = MFMA32(qfB[ks], shf[ks], acc_oB);
      }
#pragma unroll
      for (int ks = 0; ks < 4; ks++) {
        acc_oA = MFMA32(qfA[ks], slf[ks], acc_oA);
        acc_oB = MFMA32(qfB[ks], slf[ks], acc_oB);
      }

      // ---- 12. exchange A
      f16x8 ubfA = SHFL_EXCH(acc_uA);

      // ---- 13. couple B to A: u_adjB += CAB@u_adjA; oB' += DBA@u_adjA
      acc_uB = MFMA32(cabh, ubfA, acc_uB);
      acc_uB = MFMA32(cabl, ubfA, acc_uB);
      acc_oB = MFMA32(dbah, ubfA, acc_oB);
      acc_oB = MFMA32(dbal, ubfA, acc_oB);

      // ---- 14. finish oA (bit-identical A path) + store (stA group, 4)
      {
        f16x8 aah, aal;
        ATTN_SPLIT(paA0, paA1, aah, aal);
#pragma unroll
        for (int r = 0; r < 4; r++) acc_oA[r] *= QSCALE;
        acc_oA = MFMA32(aah, ubfA, acc_oA);
        acc_oA = MFMA32(aal, ubfA, acc_oA);
      }
#pragma unroll
      for (int r = 0; r < 4; r++)
        ob[(size_t)(cA * 16 + quad * 4 + r) * 256 + v0 + lc] = acc_oA[r];
      SBAR();

      // ---- 15. exchange B, finish oB + store (stB group, 4)
      f16x8 ubfB = SHFL_EXCH(acc_uB);
      {
        f16x8 bah, bal;
        ATTN_SPLIT(paB0, paB1, bah, bal);
#pragma unroll
        for (int r = 0; r < 4; r++) acc_oB[r] *= QSCALE;
        acc_oB = MFMA32(bah, ubfB, acc_oB);
        acc_oB = MFMA32(bal, ubfB, acc_oB);
      }
#pragma unroll
      for (int r = 0; r < 4; r++)
        ob[(size_t)((cA + 1) * 16 + quad * 4 + r) * 256 + v0 + lc] = acc_oB[r];
      SBAR();

      // ---- 16. mid wait: K(sc) staged.  Newer: B16+U4+W16+stA4+stB4 = 44
      if (sc + 1 < NSUPER) { WAITV(44); } else { WAITV(24); }

      // ---- 17. S += kTA@u_adjA + kTB@u_adjB
#pragma unroll
      for (int dt = 0; dt < 8; dt++) {
        f16x8 kah = *(const f16x8*)(sbA + STG_KH + dt * 256 + kswz);
        f16x8 kal = *(const f16x8*)(sbA + STG_KL + dt * 256 + kswz);
        accS[dt] = MFMA32(kah, ubfA, accS[dt]);
        accS[dt] = MFMA32(kal, ubfA, accS[dt]);
      }
#pragma unroll
      for (int dt = 0; dt < 8; dt++) {
        f16x8 kbh = *(const f16x8*)(sbB + STG_KH + dt * 256 + kswz);
        f16x8 kbl = *(const f16x8*)(sbB + STG_KL + dt * 256 + kswz);
        accS[dt] = MFMA32(kbh, ubfB, accS[dt]);
        accS[dt] = MFMA32(kbl, ubfB, accS[dt]);
      }
      SBAR();
      // ---- 18. K staging for sc+1 (kT frag reads retired above) (K group, 16)
      if (sc + 1 < NSUPER) ISSUE_K(sc + 1);
      SBAR();
    }
  }
}

// ---------------------------------------------------------------------------
// 7) Gated RMSNorm -> on f16 (o bh-major)
// ---------------------------------------------------------------------------
__global__ __launch_bounds__(256) void gate_kernel(
    const float* __restrict__ o1, const float* __restrict__ o2,
    const f16* __restrict__ qkvgHi, const float* __restrict__ norm_w,
    f16* __restrict__ onh) {
  int h = threadIdx.x >> 6, lane = threadIdx.x & 63;
  int r = blockIdx.x;              // b*L + l
  int b = r >> 11, l = r & 2047;
  int bh = b * 4 + h;
  const float* orow = ((bh < 12) ? (o1 + (size_t)bh * 524288)
                                 : (o2 + (size_t)(bh - 12) * 524288)) + (size_t)l * 256;
  int v = lane * 4;
  floatx4 ov = *(const floatx4*)&orow[v];
  float ss = ov[0] * ov[0] + ov[1] * ov[1] + ov[2] * ov[2] + ov[3] * ov[3];
  for (int m = 32; m > 0; m >>= 1) ss += __shfl_xor(ss, m);
  float rms = rsqrtf(ss * (1.0f / 256.0f) + 1e-5f);
  size_t goff = (size_t)r * 3072 + 2048 + h * 256 + v;
  floatx4 nw = *(const floatx4*)&norm_w[v];
  f16 outv[4] __attribute__((aligned(8)));
#pragma unroll
  for (int q2 = 0; q2 < 4; q2++) {
    float g = (float)qkvgHi[goff + q2];
    outv[q2] = (f16)(ov[q2] * rms * nw[q2] * (g * sigmoidf_(g)));
  }
  *(uint2*)&onh[(size_t)r * 1024 + h * 256 + v] = *(const uint2*)outv;
}

// ---------------------------------------------------------------------------
extern "C" void kernel_launch(void* const* d_in, const int* in_sizes, int n_in,
                              void* d_out, int out_size, void* d_ws, size_t ws_size,
                              hipStream_t stream) {
  (void)in_sizes; (void)n_in; (void)out_size; (void)ws_size;
  const float* hs     = (const float*)d_in[0];
  const float* conv_w = (const float*)d_in[1];
  const float* Wq     = (const float*)d_in[2];
  const float* Wk     = (const float*)d_in[3];
  const float* Wv     = (const float*)d_in[4];
  const float* Wb     = (const float*)d_in[5];
  const float* Wg     = (const float*)d_in[6];
  const float* Wo     = (const float*)d_in[7];
  const float* norm_w = (const float*)d_in[8];
  float* out = (float*)d_out;

  char* ws = (char*)d_ws;
  f16*   x_hi    = (f16*)(ws + 0);            // 16,777,216  -> uHi after GEMM1
  f16*   x_lo    = (f16*)(ws + 16777216);     // 16,777,216  -> uLo after GEMM1
  f16*   uHi     = (f16*)(ws + 0);
  f16*   uLo     = (f16*)(ws + 16777216);
  f16*   WcatHi  = (f16*)(ws + 33554432);     //  6,291,456  -> o2f after
  float* o2f     = (float*)(ws + 33554432);   //  8,388,608  (bh 12..15; spills
                                              //  2 MB into the WcatLo region —
                                              //  nothing may live there!)
  f16*   WcatLo  = (f16*)(ws + 39845888);     //  3,145,728  (kv rows only; dead
                                              //  after GEMMs, clobbered by o2f)
  f16*   WoHi    = (f16*)(ws + 42991616);     //  2,097,152
  float* betaf   = (float*)(ws + 45088768);   //    131,072
  f16*   qkvgHi  = (f16*)(ws + 45219840);     // 50,331,648  [8192][3072]
                                              //  (v-cols of rows 0..1023 hold
                                              //   CAB/DBA after cabd_kernel)
  f16*   kvLo    = (f16*)(ws + 95551488);     // 25,165,824  -> o1f after
  float* o1f     = (float*)(ws + 95551488);   // 25,165,824  (bh 0..11)
  f16*   wHi     = (f16*)(ws + 120717312);    //  8,388,608  -> on_h after scan
  f16*   on_h    = (f16*)(ws + 120717312);    // 16,777,216
  f16*   wLo     = (f16*)(ws + 129105920);    //  8,388,608
  f16*   kTHi    = (f16*)(ws + 137494528);    //  8,388,608
  f16*   kTLo    = (f16*)(ws + 145883136);    //  8,388,608
  float* attnf   = (float*)(ws + 154271744);  //  2,097,152  -> total 156,368,896

  wconv_kernel<<<2048, 256, 0, stream>>>(Wq, Wk, Wv, Wg, Wo, WcatHi, WcatLo, WoHi);
  conv_kernel<<<ROWS, 256, 0, stream>>>(hs, conv_w, x_hi, x_lo);
  beta_kernel<<<ROWS, 256, 0, stream>>>(x_hi, x_lo, Wb, betaf);
  gemm_qkvg<<<dim3(24, 64), 256, 0, stream>>>(
      x_hi, x_lo, WcatHi, WcatLo, qkvgHi, kvLo);
  prepass_kernel<<<16 * NCHUNK, 256, 0, stream>>>(
      qkvgHi, kvLo, betaf, wHi, wLo, kTHi, kTLo, uHi, uLo, attnf);
  cabd_kernel<<<16 * NSUPER, 256, 0, stream>>>(
      qkvgHi, wHi, wLo, kTHi, kTLo);
  scan_kernel<<<256, 64, 0, stream>>>(
      qkvgHi, wHi, wLo, kTHi, kTLo, attnf, uHi, uLo, o1f, o2f);
  gate_kernel<<<ROWS, 256, 0, stream>>>(o1f, o2f, qkvgHi, norm_w, on_h);
  gemm_plain<0><<<dim3(8, 64), 256, 0, stream>>>(
      on_h, WoHi, nullptr, out, 1024, 1024);
}

// Round 10
// 567.320 us; speedup vs baseline: 1.0072x; 1.0072x over previous
//
#include <hip/hip_runtime.h>
#include <cstdint>
#include <cstddef>

typedef _Float16 f16;
typedef _Float16 f16x4 __attribute__((ext_vector_type(4)));
typedef _Float16 f16x8 __attribute__((ext_vector_type(8)));
typedef float floatx4 __attribute__((ext_vector_type(4)));

#define MFMA32(a,b,c) __builtin_amdgcn_mfma_f32_16x16x32_f16((a),(b),(c),0,0,0)

#define ROWS 8192            // B*L
#define NCHUNK 128           // L/CS
#define NSUPER 64            // NCHUNK/2
// qkvgHi column order: k [0,512) | v [512,1536) | q [1536,2048) | g [2048,3072)
// After cabd_kernel, rows 0..1023 of the (dead) v-region hold the CAB/DBA
// coupling tables: row bh*64+sc, cols 512+[0,256)=CABh [256,512)=CABl
// [512,768)=DBAh [768,1024)=DBAl.
static constexpr float QSCALE = 0.08838834764831845f; // 128^-0.5

static __device__ __forceinline__ float sigmoidf_(float x) { return 1.0f / (1.0f + expf(-x)); }

static __device__ __forceinline__ uint32_t pack2(f16 a, f16 b) {
  union { f16 h[2]; uint32_t u; } v; v.h[0] = a; v.h[1] = b; return v.u;
}

// async global->LDS, 16B per lane; LDS dest is wave-uniform base (+lane*16 HW),
// global src is PER-LANE (pre-swizzled addressing lives here).
#define GLOAD_LDS(gptr, lptr)                                                  \
  __builtin_amdgcn_global_load_lds(                                            \
      (const __attribute__((address_space(1))) void*)(gptr),                   \
      (__attribute__((address_space(3))) void*)(lptr), 16, 0, 0)

// counted vmcnt wait (never drain to 0 in steady state) + scheduler fence
#define WAITV(N) do { asm volatile("s_waitcnt vmcnt(" #N ")" ::: "memory");    \
                      __builtin_amdgcn_sched_barrier(0); } while (0)

#define SBAR() __builtin_amdgcn_sched_barrier(0)

// ---------------------------------------------------------------------------
// 1) Weights -> f16. Wcat rows: [0,512)=Wk [512,1536)=Wv [1536,2048)=Wq
//    [2048,3072)=Wg. hi all; lo only k,v rows. Wo -> hi only.
// ---------------------------------------------------------------------------
__global__ __launch_bounds__(256) void wconv_kernel(
    const float* __restrict__ Wq, const float* __restrict__ Wk,
    const float* __restrict__ Wv, const float* __restrict__ Wg,
    const float* __restrict__ Wo,
    f16* __restrict__ WcatHi, f16* __restrict__ WcatLoKV, f16* __restrict__ WoHi) {
  int tid = blockIdx.x * 256 + threadIdx.x;
  int e8 = tid * 8;
  if (e8 < 3145728) {
    int row = e8 >> 10, col = e8 & 1023;
    const float* src;
    if (row < 512)       src = Wk + (size_t)row * 1024 + col;
    else if (row < 1536) src = Wv + (size_t)(row - 512) * 1024 + col;
    else if (row < 2048) src = Wq + (size_t)(row - 1536) * 1024 + col;
    else                 src = Wg + (size_t)(row - 2048) * 1024 + col;
    f16 thi[8] __attribute__((aligned(16)));
    f16 tlo[8] __attribute__((aligned(16)));
#pragma unroll
    for (int j = 0; j < 8; j++) {
      float x = src[j];
      f16 h = (f16)x;
      thi[j] = h;
      tlo[j] = (f16)(x - (float)h);
    }
    *(uint4*)&WcatHi[e8] = *(const uint4*)thi;
    if (row < 1536) *(uint4*)&WcatLoKV[e8] = *(const uint4*)tlo;
  } else {
    int idx = e8 - 3145728;
    f16 t[8] __attribute__((aligned(16)));
#pragma unroll
    for (int j = 0; j < 8; j++) t[j] = (f16)Wo[idx + j];
    *(uint4*)&WoHi[idx] = *(const uint4*)t;
  }
}

// ---------------------------------------------------------------------------
// 2) Causal depthwise conv1d (K=4) + SiLU -> x hi/lo, FUSED beta:
//    the block owns the whole row in fp32, so beta[h] = sigmoid(y . Wb[h])
//    is computed here (same tree-reduction order as the old beta_kernel) —
//    deletes one 8192-block launch and a full 33.5 MB re-read of x.
// ---------------------------------------------------------------------------
__global__ __launch_bounds__(256) void conv_kernel(
    const float* __restrict__ hs, const float* __restrict__ cw,
    const float* __restrict__ Wb,
    f16* __restrict__ xhi, f16* __restrict__ xlo, float* __restrict__ betaf) {
  int row = blockIdx.x;
  int b = row >> 11, l = row & 2047;
  int t = threadIdx.x;
  int d = t * 4;
  __shared__ floatx4 red[256];
  floatx4 w0 = *(const floatx4*)&cw[(d + 0) * 4];
  floatx4 w1 = *(const floatx4*)&cw[(d + 1) * 4];
  floatx4 w2 = *(const floatx4*)&cw[(d + 2) * 4];
  floatx4 w3 = *(const floatx4*)&cw[(d + 3) * 4];
  floatx4 acc = {0.f, 0.f, 0.f, 0.f};
#pragma unroll
  for (int j = 0; j < 4; j++) {
    int ls = l - 3 + j;
    if (ls < 0) continue;
    floatx4 hv = *(const floatx4*)&hs[(size_t)(b * 2048 + ls) * 1024 + d];
    acc[0] += hv[0] * w0[j];
    acc[1] += hv[1] * w1[j];
    acc[2] += hv[2] * w2[j];
    acc[3] += hv[3] * w3[j];
  }
  float yv[4];
  f16 ohi[4] __attribute__((aligned(8)));
  f16 olo[4] __attribute__((aligned(8)));
#pragma unroll
  for (int q = 0; q < 4; q++) {
    float y = acc[q] * sigmoidf_(acc[q]);
    yv[q] = y;
    f16 h = (f16)y;
    ohi[q] = h;
    olo[q] = (f16)(y - (float)h);
  }
  *(uint2*)&xhi[(size_t)row * 1024 + d] = *(const uint2*)ohi;
  *(uint2*)&xlo[(size_t)row * 1024 + d] = *(const uint2*)olo;
  // beta reduction (identical tree order to the old beta_kernel)
  floatx4 p = {0.f, 0.f, 0.f, 0.f};
#pragma unroll
  for (int hh = 0; hh < 4; hh++) {
    const float* wr = Wb + hh * 1024 + d;
    p[hh] = yv[0] * wr[0] + yv[1] * wr[1] + yv[2] * wr[2] + yv[3] * wr[3];
  }
  red[t] = p;
  __syncthreads();
  for (int s = 128; s > 0; s >>= 1) {
    if (t < s) red[t] += red[t + s];
    __syncthreads();
  }
  if (t < 4) betaf[(size_t)row * 4 + t] = sigmoidf_(red[0][t]);
}

// ---------------------------------------------------------------------------
// 4) MERGED x-projection GEMM, grid (24, 64).
//    blockIdx.x <  12: hi/lo path for k,v cols (3 MFMAs/tile, ChHi+ChLo)
//    blockIdx.x >= 12: plain path for q,g cols (1 MFMA/tile, ChHi only)
// ---------------------------------------------------------------------------
__global__ __launch_bounds__(256) void gemm_qkvg(
    const f16* __restrict__ Ahi, const f16* __restrict__ Alo,
    const f16* __restrict__ Bhi, const f16* __restrict__ Blo,
    f16* __restrict__ ChHi, f16* __restrict__ ChLo) {
  const int K = 1024;
  __shared__ __attribute__((aligned(16))) f16 AsH[4096];
  __shared__ __attribute__((aligned(16))) f16 AsL[4096];
  __shared__ __attribute__((aligned(16))) f16 BsH[4096];
  __shared__ __attribute__((aligned(16))) f16 BsL[4096];
  const int t = threadIdx.x;
  const int lane = t & 63, wave = t >> 6;
  const int lc = lane & 15, quad = lane >> 4;
  const int wm = (wave >> 1) * 64, wn = (wave & 1) * 64;
  const int m0 = blockIdx.y * 128, n0 = blockIdx.x * 128;
  const bool hilo = (blockIdx.x < 12);     // k,v cols carry lo corrections
  const int scol = ((lane & 3) ^ ((lane >> 3) & 3)) * 8;
  int srow[2];
#pragma unroll
  for (int pp = 0; pp < 2; pp++) srow[pp] = (wave * 2 + pp) * 16 + (lane >> 2);
  const int swz = (quad ^ ((lc >> 1) & 3)) * 8;
  floatx4 acc[4][4] = {};
  for (int kt = 0; kt < K; kt += 32) {
    __syncthreads();
#pragma unroll
    for (int pp = 0; pp < 2; pp++) {
      int ldso = (wave * 2 + pp) * 512;
      GLOAD_LDS(&Ahi[(size_t)(m0 + srow[pp]) * K + kt + scol], AsH + ldso);
      GLOAD_LDS(&Bhi[(size_t)(n0 + srow[pp]) * K + kt + scol], BsH + ldso);
      if (hilo) {
        GLOAD_LDS(&Alo[(size_t)(m0 + srow[pp]) * K + kt + scol], AsL + ldso);
        GLOAD_LDS(&Blo[(size_t)(n0 + srow[pp]) * K + kt + scol], BsL + ldso);
      }
    }
    __syncthreads();    // drains vmcnt(0) -> staged data visible
    f16x8 ah[4], bh2[4];
#pragma unroll
    for (int i = 0; i < 4; i++) ah[i] = *(const f16x8*)&AsH[(wm + i * 16 + lc) * 32 + swz];
#pragma unroll
    for (int j = 0; j < 4; j++) bh2[j] = *(const f16x8*)&BsH[(wn + j * 16 + lc) * 32 + swz];
    if (hilo) {
      f16x8 al[4], bl[4];
#pragma unroll
      for (int i = 0; i < 4; i++) al[i] = *(const f16x8*)&AsL[(wm + i * 16 + lc) * 32 + swz];
#pragma unroll
      for (int j = 0; j < 4; j++) bl[j] = *(const f16x8*)&BsL[(wn + j * 16 + lc) * 32 + swz];
#pragma unroll
      for (int i = 0; i < 4; i++)
#pragma unroll
        for (int j = 0; j < 4; j++) {
          acc[i][j] = MFMA32(ah[i], bh2[j], acc[i][j]);
          acc[i][j] = MFMA32(al[i], bh2[j], acc[i][j]);
          acc[i][j] = MFMA32(ah[i], bl[j], acc[i][j]);
        }
    } else {
#pragma unroll
      for (int i = 0; i < 4; i++)
#pragma unroll
        for (int j = 0; j < 4; j++) acc[i][j] = MFMA32(ah[i], bh2[j], acc[i][j]);
    }
  }
#pragma unroll
  for (int i = 0; i < 4; i++)
#pragma unroll
    for (int j = 0; j < 4; j++)
#pragma unroll
      for (int rr = 0; rr < 4; rr++) {
        int row = m0 + wm + i * 16 + quad * 4 + rr;
        int col = n0 + wn + j * 16 + lc;
        float x = acc[i][j][rr];
        f16 h = (f16)x;
        ChHi[(size_t)row * 3072 + col] = h;
        if (hilo) ChLo[(size_t)row * 1536 + col] = (f16)(x - (float)h);
      }
}

// ---------------------------------------------------------------------------
// 4b) Plain f16 GEMM (global_load_lds staging) — output projection only.
// ---------------------------------------------------------------------------
template <int OUTF16>
__global__ __launch_bounds__(256) void gemm_plain(
    const f16* __restrict__ A, const f16* __restrict__ Bw,
    f16* __restrict__ Ch, float* __restrict__ Cf, int K, int ldc) {
  __shared__ __attribute__((aligned(16))) f16 As[4096];
  __shared__ __attribute__((aligned(16))) f16 Bs[4096];
  const int t = threadIdx.x;
  const int lane = t & 63, wave = t >> 6;
  const int lc = lane & 15, quad = lane >> 4;
  const int wm = (wave >> 1) * 64, wn = (wave & 1) * 64;
  const int m0 = blockIdx.y * 128, n0 = blockIdx.x * 128;
  const int scol = ((lane & 3) ^ ((lane >> 3) & 3)) * 8;
  int srow[2];
#pragma unroll
  for (int pp = 0; pp < 2; pp++) srow[pp] = (wave * 2 + pp) * 16 + (lane >> 2);
  const int swz = (quad ^ ((lc >> 1) & 3)) * 8;
  floatx4 acc[4][4] = {};
  for (int kt = 0; kt < K; kt += 32) {
    __syncthreads();
#pragma unroll
    for (int pp = 0; pp < 2; pp++) {
      int ldso = (wave * 2 + pp) * 512;
      GLOAD_LDS(&A[(size_t)(m0 + srow[pp]) * K + kt + scol],  As + ldso);
      GLOAD_LDS(&Bw[(size_t)(n0 + srow[pp]) * K + kt + scol], Bs + ldso);
    }
    __syncthreads();
    f16x8 af[4], bf[4];
#pragma unroll
    for (int i = 0; i < 4; i++) af[i] = *(const f16x8*)&As[(wm + i * 16 + lc) * 32 + swz];
#pragma unroll
    for (int j = 0; j < 4; j++) bf[j] = *(const f16x8*)&Bs[(wn + j * 16 + lc) * 32 + swz];
#pragma unroll
    for (int i = 0; i < 4; i++)
#pragma unroll
      for (int j = 0; j < 4; j++) acc[i][j] = MFMA32(af[i], bf[j], acc[i][j]);
  }
#pragma unroll
  for (int i = 0; i < 4; i++)
#pragma unroll
    for (int j = 0; j < 4; j++)
#pragma unroll
      for (int rr = 0; rr < 4; rr++) {
        int row = m0 + wm + i * 16 + quad * 4 + rr;
        int col = n0 + wn + j * 16 + lc;
        if (OUTF16) Ch[(size_t)row * ldc + col] = (f16)acc[i][j][rr];
        else        Cf[(size_t)row * ldc + col] = acc[i][j][rr];
      }
}

// ---------------------------------------------------------------------------
// 5) Chunk pre-pass (unchanged).
// ---------------------------------------------------------------------------
__global__ __launch_bounds__(256) void prepass_kernel(
    const f16* __restrict__ qkvgHi, const f16* __restrict__ kvLo,
    const float* __restrict__ betaf,
    f16* __restrict__ wHi, f16* __restrict__ wLo,
    f16* __restrict__ kTHi, f16* __restrict__ kTLo,
    f16* __restrict__ uHi, f16* __restrict__ uLo,
    float* __restrict__ attno) {
  int bid = blockIdx.x;          // 16*128
  int bh = bid >> 7, n = bid & 127;
  int b = bh >> 2, h = bh & 3;
  int t = threadIdx.x;

  __shared__ __attribute__((aligned(16))) float kc[16][132];
  __shared__ __attribute__((aligned(16))) float qc[16][132];
  __shared__ __attribute__((aligned(16))) float vb[16][260];
  __shared__ float Mm[16][16];
  __shared__ float Tt[16][16];
  __shared__ float Tb[16][16];
  __shared__ float part[16][16];
  __shared__ float betas[16];
  __shared__ float nrm[16];

  const size_t rowbase = (size_t)(b * 2048 + n * 16);
  {
    int i = t >> 4, o8 = (t & 15) * 8;
    size_t oh = (rowbase + i) * 3072;
    size_t ol = (rowbase + i) * 1536;
#pragma unroll
    for (int j = 0; j < 8; j++)
      kc[i][o8 + j] = (float)qkvgHi[oh + h * 128 + o8 + j] +
                      (float)kvLo[ol + h * 128 + o8 + j];
#pragma unroll
    for (int j = 0; j < 8; j++)
      qc[i][o8 + j] = (float)qkvgHi[oh + 1536 + h * 128 + o8 + j];
  }
  if (t < 16) betas[t] = betaf[(rowbase + t) * 4 + h];
  __syncthreads();
  {
    int i = t >> 4, sg = t & 15;
    float s = 0.f;
#pragma unroll
    for (int j = 0; j < 8; j++) { float v = kc[i][sg * 8 + j]; s += v * v; }
    part[i][sg] = s;
  }
  __syncthreads();
  if (t < 16) {
    float s = 0.f;
#pragma unroll
    for (int j = 0; j < 16; j++) s += part[t][j];
    nrm[t] = rsqrtf(s + 1e-12f);
  }
  __syncthreads();
  {
    int i = t >> 4, o8 = (t & 15) * 8;
    float sc = nrm[i];
#pragma unroll
    for (int j = 0; j < 8; j++) kc[i][o8 + j] *= sc;
  }
  __syncthreads();
  { // kT: normalized k transposed [d][token], hi/lo
    int d = t & 127, ih = t >> 7;
    f16 thi[8] __attribute__((aligned(16)));
    f16 tlo[8] __attribute__((aligned(16)));
#pragma unroll
    for (int j = 0; j < 8; j++) {
      float x = kc[ih * 8 + j][d];
      f16 hh = (f16)x;
      thi[j] = hh;
      tlo[j] = (f16)(x - (float)hh);
    }
    size_t base = ((size_t)bh * 128 + n) * 2048 + d * 16 + ih * 8;
    *(uint4*)&kTHi[base] = *(const uint4*)thi;
    *(uint4*)&kTLo[base] = *(const uint4*)tlo;
  }
  { // M = I + beta_i * (k_i . k_j) strictly-lower
    int i = t >> 4, j = t & 15;
    float s = 0.f;
    for (int x = 0; x < 128; x += 4)
      s += kc[i][x] * kc[j][x] + kc[i][x + 1] * kc[j][x + 1] +
           kc[i][x + 2] * kc[j][x + 2] + kc[i][x + 3] * kc[j][x + 3];
    Mm[i][j] = (i == j ? 1.f : 0.f) + ((j < i) ? betas[i] * s : 0.f);
  }
  __syncthreads();
  if (t < 16) { // forward substitution, column t of T = M^-1
    int j = t;
    float Tc[16];
#pragma unroll
    for (int i = 0; i < 16; i++) Tc[i] = 0.f;
    Tc[j] = 1.f;
    for (int i = j + 1; i < 16; i++) {
      float s = 0.f;
      for (int k2 = j; k2 < i; k2++) s += Mm[i][k2] * Tc[k2];
      Tc[i] = -s;
    }
    for (int i = 0; i < 16; i++) Tt[i][j] = Tc[i];
  }
  __syncthreads();
  { int i = t >> 4, m = t & 15; Tb[i][m] = Tt[i][m] * betas[m]; }
  { // vb = v * beta
    int m = t >> 4, c16 = (t & 15) * 16;
    size_t oh = (rowbase + m) * 3072 + 512 + h * 256 + c16;
    size_t ol = (rowbase + m) * 1536 + 512 + h * 256 + c16;
    float bm = betas[m];
#pragma unroll
    for (int j = 0; j < 16; j++)
      vb[m][c16 + j] = bm * ((float)qkvgHi[oh + j] + (float)kvLo[ol + j]);
  }
  __syncthreads();
  { // -w = -(Tb @ k_norm), hi/lo
    int i = t >> 4, dg = t & 15;
    f16 thi[8] __attribute__((aligned(16)));
    f16 tlo[8] __attribute__((aligned(16)));
#pragma unroll
    for (int dd = 0; dd < 8; dd++) {
      int d = dg * 8 + dd;
      float s = 0.f;
#pragma unroll
      for (int m = 0; m < 16; m++) s += Tb[i][m] * kc[m][d];
      s = -s;
      f16 hh = (f16)s;
      thi[dd] = hh;
      tlo[dd] = (f16)(s - (float)hh);
    }
    size_t base = ((size_t)bh * 128 + n) * 2048 + i * 128 + dg * 8;
    *(uint4*)&wHi[base] = *(const uint4*)thi;
    *(uint4*)&wLo[base] = *(const uint4*)tlo;
  }
  { // u = Tt @ vb, hi/lo, chunk-TRANSPOSED out: [vg][bh][n][vv][i]
    int v = t;
    f16 thi[16] __attribute__((aligned(16)));
    f16 tlo[16] __attribute__((aligned(16)));
#pragma unroll
    for (int i = 0; i < 16; i++) {
      float s2 = 0.f;
#pragma unroll
      for (int m = 0; m < 16; m++) s2 += Tt[i][m] * vb[m][v];
      f16 hh = (f16)s2;
      thi[i] = hh;
      tlo[i] = (f16)(s2 - (float)hh);
    }
    size_t base = ((((size_t)(v >> 4) * 16 + bh) * 128 + n) * 16 + (v & 15)) * 16;
    ((uint4*)&uHi[base])[0] = ((const uint4*)thi)[0];
    ((uint4*)&uHi[base])[1] = ((const uint4*)thi)[1];
    ((uint4*)&uLo[base])[0] = ((const uint4*)tlo)[0];
    ((uint4*)&uLo[base])[1] = ((const uint4*)tlo)[1];
  }
  { // attn = qscale * (q . k_norm), causal inclusive, fp32
    int i = t >> 4, j = t & 15;
    float s = 0.f;
    for (int x = 0; x < 128; x++) s += qc[i][x] * kc[j][x];
    attno[((size_t)bh * 128 + n) * 256 + i * 16 + j] = (j <= i) ? QSCALE * s : 0.f;
  }
}

// ---------------------------------------------------------------------------
// 5b) Pair-coupling pre-pass (unchanged): CAB = (-wB)@kTA, DBA = qB@kTA,
//     stored in qkvgHi's dead v-region (row bh*64+sc, col 512+...).
// ---------------------------------------------------------------------------
__global__ __launch_bounds__(256) void cabd_kernel(
    f16* qkvg,
    const f16* __restrict__ wHi, const f16* __restrict__ wLo,
    const f16* __restrict__ kTHi, const f16* __restrict__ kTLo) {
  int bid = blockIdx.x;            // 16*64
  int bh = bid >> 6, sc = bid & 63;
  int b = bh >> 2, h = bh & 3;
  int t = threadIdx.x;
  int cA = 2 * sc, cB = 2 * sc + 1;
  const size_t cb = (size_t)bh * 128;

  __shared__ float wf[16][128];
  __shared__ float qf[16][128];
  __shared__ float kf[128][17];

  {
    int i = t >> 4, d0 = (t & 15) * 8;
    size_t wbase = (cb + cB) * 2048 + i * 128 + d0;
    size_t qbase = ((size_t)b * 2048 + cB * 16 + i) * 3072 + 1536 + h * 128 + d0;
#pragma unroll
    for (int j = 0; j < 8; j++) {
      wf[i][d0 + j] = (float)wHi[wbase + j] + (float)wLo[wbase + j];
      qf[i][d0 + j] = (float)qkvg[qbase + j];
    }
    int d = t >> 1, tk0 = (t & 1) * 8;
    size_t kb = (cb + cA) * 2048 + d * 16 + tk0;
#pragma unroll
    for (int j = 0; j < 8; j++)
      kf[d][tk0 + j] = (float)kTHi[kb + j] + (float)kTLo[kb + j];
  }
  __syncthreads();
  int i = t >> 4, j = t & 15;
  float sc1 = 0.f, sd1 = 0.f;
  for (int d = 0; d < 128; d++) {
    float kv = kf[d][j];
    sc1 += wf[i][d] * kv;
    sd1 += qf[i][d] * kv;
  }
  f16 ch = (f16)sc1, dh = (f16)sd1;
  size_t o = (size_t)(bh * 64 + sc) * 3072 + 512 + i * 16 + j;
  qkvg[o]       = ch;  qkvg[o + 256] = (f16)(sc1 - (float)ch);
  qkvg[o + 512] = dh;  qkvg[o + 768] = (f16)(sd1 - (float)dh);
}

// ---------------------------------------------------------------------------
// 6) Delta-rule scan, SUPERCHUNK-2 — ROUND-7 body (measured best, 177.5 us),
//    with o stored as f16 into ONE unified buffer [bh][l][256] (halves o
//    write traffic; removes the o1f/o2f split).  Stores stay at the o-finish
//    (steps 14/15) — R8 showed deferring them regresses.
//    vmcnt ledger (groups fenced): B16 U4 W16 stA4 stB4 K16 = 60/body.
//      top WAITV(16); mid WAITV(44) (sc==63: 24); peaks <= 60 <= 63.
// ---------------------------------------------------------------------------
#define STG_W   0
#define STG_WL  2048
#define STG_KH  4096
#define STG_KL  6144
#define STG_CH  8192     // f16 per chunk buffer (16KB)

__global__ __launch_bounds__(64, 1) void scan_kernel(
    const f16* __restrict__ qkvgHi,
    const f16* __restrict__ wHi, const f16* __restrict__ wLo,
    const f16* __restrict__ kTHi, const f16* __restrict__ kTLo,
    const float* __restrict__ attn,
    const f16* __restrict__ uHi, const f16* __restrict__ uLo,
    f16* __restrict__ of) {
  const int bid = blockIdx.x;
  const int slc = bid >> 4, bh = bid & 15;   // XCD-local: bid%8 = bh%8
  const int b = bh >> 2, h = bh & 3;
  const int v0 = slc * 16;
  const int lane = threadIdx.x;
  const int lc = lane & 15, quad = lane >> 4;
  const int qh = quad & 1;

  __shared__ __attribute__((aligned(16))) f16 stg[2][STG_CH];  // [chunk-in-pair]
  __shared__ __attribute__((aligned(16))) f16 S_hi[16][136];
  __shared__ __attribute__((aligned(16))) f16 S_lo[16][136];

  floatx4 accS[8] = {};   // S[dt*16 + quad*4 + r][v0 + lc]

  const size_t cb = (size_t)bh * 128;
  const f16* qb = qkvgHi + (size_t)b * 2048 * 3072 + 1536 + h * 128;
  const f16* ubH = uHi + ((size_t)(slc * 16 + bh)) * 32768 + lc * 16 + quad * 4;
  const f16* ubL = uLo + ((size_t)(slc * 16 + bh)) * 32768 + lc * 16 + quad * 4;
  const float* ab = attn + cb * 256 + lc * 16 + qh * 8;
  // CAB/DBA tables in qkvgHi v-region: row bh*64+sc, col 512+...
  const f16* cd = qkvgHi + (size_t)(bh * 64) * 3072 + 512 + lc * 16 + qh * 8;
  f16* ob = of + (size_t)bh * 2048 * 256;

  // per-lane swizzled source offsets (chunk-invariant)
  int woff[4], koff[4];
#pragma unroll
  for (int p = 0; p < 4; p++) {
    int cid = p * 64 + lane;
    int row = cid >> 4, dgs = (cid & 15) ^ (row & 7);
    int d = cid >> 1,  ih = (cid & 1) ^ ((cid >> 3) & 1);
    woff[p] = row * 128 + dgs * 8;
    koff[p] = d * 16 + ih * 8;
  }

  // u prefetch, 2 slots (the only cross-body register prefetch)
  uint2 puhA[2], pulA[2], puhB[2], pulB[2];

  auto ISSUE_U = [&](int slot, int sc) {   // 4 VMEM
    puhA[slot] = *(const uint2*)(ubH + (size_t)(2 * sc) * 256);
    pulA[slot] = *(const uint2*)(ubL + (size_t)(2 * sc) * 256);
    puhB[slot] = *(const uint2*)(ubH + (size_t)(2 * sc + 1) * 256);
    pulB[slot] = *(const uint2*)(ubL + (size_t)(2 * sc + 1) * 256);
  };
  auto ISSUE_W = [&](int sc) {   // 16 gloads (both chunks)
#pragma unroll
    for (int ci = 0; ci < 2; ci++) {
      const f16* ws = wHi + (cb + (size_t)(2 * sc + ci)) * 2048;
      const f16* wl = wLo + (cb + (size_t)(2 * sc + ci)) * 2048;
      f16* sbp = &stg[ci][0];
#pragma unroll
      for (int p = 0; p < 4; p++) {
        GLOAD_LDS(ws + woff[p], sbp + STG_W  + p * 512);
        GLOAD_LDS(wl + woff[p], sbp + STG_WL + p * 512);
      }
    }
  };
  auto ISSUE_K = [&](int sc) {   // 16 gloads (both chunks)
#pragma unroll
    for (int ci = 0; ci < 2; ci++) {
      const f16* kh = kTHi + (cb + (size_t)(2 * sc + ci)) * 2048;
      const f16* kl = kTLo + (cb + (size_t)(2 * sc + ci)) * 2048;
      f16* sbp = &stg[ci][0];
#pragma unroll
      for (int p = 0; p < 4; p++) {
        GLOAD_LDS(kh + koff[p], sbp + STG_KH + p * 512);
        GLOAD_LDS(kl + koff[p], sbp + STG_KL + p * 512);
      }
    }
  };

  auto SHFL_EXCH = [&](floatx4 acc_u) -> f16x8 {
    f16 h0 = (f16)acc_u[0], h1 = (f16)acc_u[1];
    f16 h2 = (f16)acc_u[2], h3 = (f16)acc_u[3];
    uint32_t uh01 = pack2(h0, h1), uh23 = pack2(h2, h3);
    uint32_t ul01 = pack2((f16)(acc_u[0] - (float)h0), (f16)(acc_u[1] - (float)h1));
    uint32_t ul23 = pack2((f16)(acc_u[2] - (float)h2), (f16)(acc_u[3] - (float)h3));
    int srcA = (2 * qh) * 16 + lc;
    int srcB = srcA + 16;
    uint32_t Ah0 = __shfl((int)uh01, srcA, 64), Ah1 = __shfl((int)uh23, srcA, 64);
    uint32_t Bh0 = __shfl((int)uh01, srcB, 64), Bh1 = __shfl((int)uh23, srcB, 64);
    uint32_t Al0 = __shfl((int)ul01, srcA, 64), Al1 = __shfl((int)ul23, srcA, 64);
    uint32_t Bl0 = __shfl((int)ul01, srcB, 64), Bl1 = __shfl((int)ul23, srcB, 64);
    union { uint32_t u[4]; f16x8 v; } U;
    bool hi = (quad < 2);
    U.u[0] = hi ? Ah0 : Al0;
    U.u[1] = hi ? Ah1 : Al1;
    U.u[2] = hi ? Bh0 : Bl0;
    U.u[3] = hi ? Bh1 : Bl1;
    return U.v;
  };

  // attn fp32x8 -> hi/lo f16x8 frags
  auto ATTN_SPLIT = [&](uint4 p0, uint4 p1, f16x8& hh, f16x8& ll) {
    union { uint4 u4[2]; float f[8]; } PA;
    PA.u4[0] = p0; PA.u4[1] = p1;
#pragma unroll
    for (int j = 0; j < 8; j++) {
      float a = PA.f[j];
      f16 ah = (f16)a;
      hh[j] = ah;
      ll[j] = (f16)(a - (float)ah);
    }
  };

  const int kswz = (qh ^ ((lc >> 2) & 1)) * 8 + lc * 16;

  // prologue: superchunk 0 fully in flight (U4 + W16 + K16 = 36)
  ISSUE_U(0, 0); SBAR();
  ISSUE_W(0);    SBAR();
  ISSUE_K(0);    SBAR();

  for (int s2 = 0; s2 < NSUPER; s2 += 2) {
#pragma unroll
    for (int half = 0; half < 2; half++) {
      const int sc = s2 + half;
      const int slot = half;           // = sc & 1
      const int cA = 2 * sc;

      // ---- 1. dump S (state after superchunk sc-1) hi/lo to LDS
#pragma unroll
      for (int dt = 0; dt < 8; dt++) {
        f16x4 h4, l4;
#pragma unroll
        for (int r = 0; r < 4; r++) {
          float x = accS[dt][r];
          f16 hh = (f16)x;
          h4[r] = hh;
          l4[r] = (f16)(x - (float)hh);
        }
        *(f16x4*)&S_hi[lc][dt * 16 + quad * 4] = h4;
        *(f16x4*)&S_lo[lc][dt * 16 + quad * 4] = l4;
      }

      // ---- 2. top wait: W(sc)+U(sc) staged (16 = K(sc) left outstanding)
      WAITV(16);

      // ---- 3. same-body register loads: attn, CAB/DBA, q (B group, 16)
      uint4 paA0 = *(const uint4*)(ab + (size_t)cA * 256);
      uint4 paA1 = *(const uint4*)(ab + (size_t)cA * 256 + 4);
      uint4 paB0 = *(const uint4*)(ab + (size_t)(cA + 1) * 256);
      uint4 paB1 = *(const uint4*)(ab + (size_t)(cA + 1) * 256 + 4);
      const f16* cdp = cd + (size_t)sc * 3072;
      f16x8 cabh = *(const f16x8*)(cdp);
      f16x8 cabl = *(const f16x8*)(cdp + 256);
      f16x8 dbah = *(const f16x8*)(cdp + 512);
      f16x8 dbal = *(const f16x8*)(cdp + 768);
      f16x8 qfA[4], qfB[4];
#pragma unroll
      for (int ks = 0; ks < 4; ks++) {
        qfA[ks] = *(const f16x8*)(qb + (size_t)(cA * 16 + lc) * 3072 + ks * 32 + quad * 8);
        qfB[ks] = *(const f16x8*)(qb + (size_t)((cA + 1) * 16 + lc) * 3072 + ks * 32 + quad * 8);
      }
      SBAR();

      // ---- 4. consume u prefetch
      floatx4 acc_uA, acc_uB;
      {
        union { uint2 u2; f16 hh[4]; } Uh, Ul;
        Uh.u2 = puhA[slot]; Ul.u2 = pulA[slot];
#pragma unroll
        for (int r = 0; r < 4; r++) acc_uA[r] = (float)Uh.hh[r] + (float)Ul.hh[r];
        Uh.u2 = puhB[slot]; Ul.u2 = pulB[slot];
#pragma unroll
        for (int r = 0; r < 4; r++) acc_uB[r] = (float)Uh.hh[r] + (float)Ul.hh[r];
      }
      // ---- 5. next-superchunk u prefetch (U group, 4)
      if (sc + 1 < NSUPER) ISSUE_U(slot ^ 1, sc + 1);
      SBAR();

      // ---- 6. S frags + wA frags
      f16x8 shf[4], slf[4], wah[4], wal[4];
      f16* sbA = &stg[0][0];
      f16* sbB = &stg[1][0];
#pragma unroll
      for (int ks = 0; ks < 4; ks++) {
        shf[ks] = *(const f16x8*)&S_hi[lc][ks * 32 + quad * 8];
        slf[ks] = *(const f16x8*)&S_lo[lc][ks * 32 + quad * 8];
        int gi = lc * 128 + (((ks * 4 + quad) ^ (lc & 7)) * 8);
        wah[ks] = *(const f16x8*)(sbA + STG_W  + gi);
        wal[ks] = *(const f16x8*)(sbA + STG_WL + gi);
      }
      // ---- 7. yA trio (bit-identical A path)
      floatx4 a1 = {0.f,0.f,0.f,0.f}, a2 = {0.f,0.f,0.f,0.f};
#pragma unroll
      for (int ks = 0; ks < 4; ks++) {
        acc_uA = MFMA32(wah[ks], shf[ks], acc_uA);
        a1     = MFMA32(wah[ks], slf[ks], a1);
        a2     = MFMA32(wal[ks], shf[ks], a2);
      }
      acc_uA = acc_uA + a1 + a2;

      // ---- 8. wB frags
      f16x8 wbh[4], wbl[4];
#pragma unroll
      for (int ks = 0; ks < 4; ks++) {
        int gi = lc * 128 + (((ks * 4 + quad) ^ (lc & 7)) * 8);
        wbh[ks] = *(const f16x8*)(sbB + STG_W  + gi);
        wbl[ks] = *(const f16x8*)(sbB + STG_WL + gi);
      }
      // ---- 9. yB trio
      floatx4 b1 = {0.f,0.f,0.f,0.f}, b2 = {0.f,0.f,0.f,0.f};
#pragma unroll
      for (int ks = 0; ks < 4; ks++) {
        acc_uB = MFMA32(wbh[ks], shf[ks], acc_uB);
        b1     = MFMA32(wbh[ks], slf[ks], b1);
        b2     = MFMA32(wbl[ks], shf[ks], b2);
      }
      acc_uB = acc_uB + b1 + b2;
      SBAR();
      // ---- 10. W staging for sc+1 (w frag reads retired above) (W group, 16)
      if (sc + 1 < NSUPER) ISSUE_W(sc + 1);
      SBAR();

      // ---- 11. oA' = qA@S, oB' = qB@S (parallel filler)
      floatx4 acc_oA = {0.f,0.f,0.f,0.f}, acc_oB = {0.f,0.f,0.f,0.f};
#pragma unroll
      for (int ks = 0; ks < 4; ks++) {
        acc_oA = MFMA32(qfA[ks], shf[ks], acc_oA);
        acc_oB = MFMA32(qfB[ks], shf[ks], acc_oB);
      }
#pragma unroll
      for (int ks = 0; ks < 4; ks++) {
        acc_oA = MFMA32(qfA[ks], slf[ks], acc_oA);
        acc_oB = MFMA32(qfB[ks], slf[ks], acc_oB);
      }

      // ---- 12. exchange A
      f16x8 ubfA = SHFL_EXCH(acc_uA);

      // ---- 13. couple B to A: u_adjB += CAB@u_adjA; oB' += DBA@u_adjA
      acc_uB = MFMA32(cabh, ubfA, acc_uB);
      acc_uB = MFMA32(cabl, ubfA, acc_uB);
      acc_oB = MFMA32(dbah, ubfA, acc_oB);
      acc_oB = MFMA32(dbal, ubfA, acc_oB);

      // ---- 14. finish oA (bit-identical A path) + store f16 (stA group, 4)
      {
        f16x8 aah, aal;
        ATTN_SPLIT(paA0, paA1, aah, aal);
#pragma unroll
        for (int r = 0; r < 4; r++) acc_oA[r] *= QSCALE;
        acc_oA = MFMA32(aah, ubfA, acc_oA);
        acc_oA = MFMA32(aal, ubfA, acc_oA);
      }
#pragma unroll
      for (int r = 0; r < 4; r++)
        ob[(size_t)(cA * 16 + quad * 4 + r) * 256 + v0 + lc] = (f16)acc_oA[r];
      SBAR();

      // ---- 15. exchange B, finish oB + store f16 (stB group, 4)
      f16x8 ubfB = SHFL_EXCH(acc_uB);
      {
        f16x8 bah, bal;
        ATTN_SPLIT(paB0, paB1, bah, bal);
#pragma unroll
        for (int r = 0; r < 4; r++) acc_oB[r] *= QSCALE;
        acc_oB = MFMA32(bah, ubfB, acc_oB);
        acc_oB = MFMA32(bal, ubfB, acc_oB);
      }
#pragma unroll
      for (int r = 0; r < 4; r++)
        ob[(size_t)((cA + 1) * 16 + quad * 4 + r) * 256 + v0 + lc] = (f16)acc_oB[r];
      SBAR();

      // ---- 16. mid wait: K(sc) staged.  Newer: B16+U4+W16+stA4+stB4 = 44
      if (sc + 1 < NSUPER) { WAITV(44); } else { WAITV(24); }

      // ---- 17. S += kTA@u_adjA + kTB@u_adjB
#pragma unroll
      for (int dt = 0; dt < 8; dt++) {
        f16x8 kah = *(const f16x8*)(sbA + STG_KH + dt * 256 + kswz);
        f16x8 kal = *(const f16x8*)(sbA + STG_KL + dt * 256 + kswz);
        accS[dt] = MFMA32(kah, ubfA, accS[dt]);
        accS[dt] = MFMA32(kal, ubfA, accS[dt]);
      }
#pragma unroll
      for (int dt = 0; dt < 8; dt++) {
        f16x8 kbh = *(const f16x8*)(sbB + STG_KH + dt * 256 + kswz);
        f16x8 kbl = *(const f16x8*)(sbB + STG_KL + dt * 256 + kswz);
        accS[dt] = MFMA32(kbh, ubfB, accS[dt]);
        accS[dt] = MFMA32(kbl, ubfB, accS[dt]);
      }
      SBAR();
      // ---- 18. K staging for sc+1 (kT frag reads retired above) (K group, 16)
      if (sc + 1 < NSUPER) ISSUE_K(sc + 1);
      SBAR();
    }
  }
}

// ---------------------------------------------------------------------------
// 7) Gated RMSNorm -> on f16 (o f16, unified bh-major buffer)
// ---------------------------------------------------------------------------
__global__ __launch_bounds__(256) void gate_kernel(
    const f16* __restrict__ of,
    const f16* __restrict__ qkvgHi, const float* __restrict__ norm_w,
    f16* __restrict__ onh) {
  int h = threadIdx.x >> 6, lane = threadIdx.x & 63;
  int r = blockIdx.x;              // b*L + l
  int b = r >> 11, l = r & 2047;
  int bh = b * 4 + h;
  const f16* orow = of + ((size_t)bh * 2048 + l) * 256;
  int v = lane * 4;
  float ov[4];
  {
    union { uint2 u2; f16 hh[4]; } O;
    O.u2 = *(const uint2*)&orow[v];
#pragma unroll
    for (int j = 0; j < 4; j++) ov[j] = (float)O.hh[j];
  }
  float ss = ov[0] * ov[0] + ov[1] * ov[1] + ov[2] * ov[2] + ov[3] * ov[3];
  for (int m = 32; m > 0; m >>= 1) ss += __shfl_xor(ss, m);
  float rms = rsqrtf(ss * (1.0f / 256.0f) + 1e-5f);
  size_t goff = (size_t)r * 3072 + 2048 + h * 256 + v;
  floatx4 nw = *(const floatx4*)&norm_w[v];
  f16 outv[4] __attribute__((aligned(8)));
#pragma unroll
  for (int q2 = 0; q2 < 4; q2++) {
    float g = (float)qkvgHi[goff + q2];
    outv[q2] = (f16)(ov[q2] * rms * nw[q2] * (g * sigmoidf_(g)));
  }
  *(uint2*)&onh[(size_t)r * 1024 + h * 256 + v] = *(const uint2*)outv;
}

// ---------------------------------------------------------------------------
extern "C" void kernel_launch(void* const* d_in, const int* in_sizes, int n_in,
                              void* d_out, int out_size, void* d_ws, size_t ws_size,
                              hipStream_t stream) {
  (void)in_sizes; (void)n_in; (void)out_size; (void)ws_size;
  const float* hs     = (const float*)d_in[0];
  const float* conv_w = (const float*)d_in[1];
  const float* Wq     = (const float*)d_in[2];
  const float* Wk     = (const float*)d_in[3];
  const float* Wv     = (const float*)d_in[4];
  const float* Wb     = (const float*)d_in[5];
  const float* Wg     = (const float*)d_in[6];
  const float* Wo     = (const float*)d_in[7];
  const float* norm_w = (const float*)d_in[8];
  float* out = (float*)d_out;

  char* ws = (char*)d_ws;
  f16*   x_hi    = (f16*)(ws + 0);            // 16,777,216  -> uHi after GEMM
  f16*   x_lo    = (f16*)(ws + 16777216);     // 16,777,216  -> uLo after GEMM
  f16*   uHi     = (f16*)(ws + 0);
  f16*   uLo     = (f16*)(ws + 16777216);
  f16*   WcatHi  = (f16*)(ws + 33554432);     //  6,291,456
  f16*   WcatLo  = (f16*)(ws + 39845888);     //  3,145,728  (kv rows only)
  f16*   WoHi    = (f16*)(ws + 42991616);     //  2,097,152
  float* betaf   = (float*)(ws + 45088768);   //    131,072
  f16*   qkvgHi  = (f16*)(ws + 45219840);     // 50,331,648  [8192][3072]
                                              //  (v-cols of rows 0..1023 hold
                                              //   CAB/DBA after cabd_kernel)
  f16*   kvLo    = (f16*)(ws + 95551488);     // 25,165,824  -> of16 after
  f16*   of16    = (f16*)(ws + 95551488);     // 16,777,216  [16][2048][256] f16
  f16*   wHi     = (f16*)(ws + 120717312);    //  8,388,608  -> on_h after scan
  f16*   on_h    = (f16*)(ws + 120717312);    // 16,777,216
  f16*   wLo     = (f16*)(ws + 129105920);    //  8,388,608
  f16*   kTHi    = (f16*)(ws + 137494528);    //  8,388,608
  f16*   kTLo    = (f16*)(ws + 145883136);    //  8,388,608
  float* attnf   = (float*)(ws + 154271744);  //  2,097,152  -> total 156,368,896

  wconv_kernel<<<2048, 256, 0, stream>>>(Wq, Wk, Wv, Wg, Wo, WcatHi, WcatLo, WoHi);
  conv_kernel<<<ROWS, 256, 0, stream>>>(hs, conv_w, Wb, x_hi, x_lo, betaf);
  gemm_qkvg<<<dim3(24, 64), 256, 0, stream>>>(
      x_hi, x_lo, WcatHi, WcatLo, qkvgHi, kvLo);
  prepass_kernel<<<16 * NCHUNK, 256, 0, stream>>>(
      qkvgHi, kvLo, betaf, wHi, wLo, kTHi, kTLo, uHi, uLo, attnf);
  cabd_kernel<<<16 * NSUPER, 256, 0, stream>>>(
      qkvgHi, wHi, wLo, kTHi, kTLo);
  scan_kernel<<<256, 64, 0, stream>>>(
      qkvgHi, wHi, wLo, kTHi, kTLo, attnf, uHi, uLo, of16);
  gate_kernel<<<ROWS, 256, 0, stream>>>(of16, qkvgHi, norm_w, on_h);
  gemm_plain<0><<<dim3(8, 64), 256, 0, stream>>>(
      on_h, WoHi, nullptr, out, 1024, 1024);
}

// Round 11
// 558.976 us; speedup vs baseline: 1.0222x; 1.0149x over previous
//
#include <hip/hip_runtime.h>
#include <cstdint>
#include <cstddef>

typedef _Float16 f16;
typedef _Float16 f16x4 __attribute__((ext_vector_type(4)));
typedef _Float16 f16x8 __attribute__((ext_vector_type(8)));
typedef float floatx4 __attribute__((ext_vector_type(4)));

#define MFMA32(a,b,c) __builtin_amdgcn_mfma_f32_16x16x32_f16((a),(b),(c),0,0,0)

#define ROWS 8192            // B*L
#define NCHUNK 128           // L/CS
#define NSUPER 64            // NCHUNK/2
// qkvgHi column order: k [0,512) | v [512,1536) | q [1536,2048) | g [2048,3072)
// After cabd_kernel, rows 0..1023 of the (dead) v-region hold the CAB/DBA
// coupling tables: row bh*64+sc, cols 512+[0,256)=CABh [256,512)=CABl
// [512,768)=DBAh [768,1024)=DBAl.
static constexpr float QSCALE = 0.08838834764831845f; // 128^-0.5

static __device__ __forceinline__ float sigmoidf_(float x) { return 1.0f / (1.0f + expf(-x)); }

static __device__ __forceinline__ uint32_t pack2(f16 a, f16 b) {
  union { f16 h[2]; uint32_t u; } v; v.h[0] = a; v.h[1] = b; return v.u;
}

// async global->LDS, 16B per lane; LDS dest is wave-uniform base (+lane*16 HW),
// global src is PER-LANE (pre-swizzled addressing lives here).
#define GLOAD_LDS(gptr, lptr)                                                  \
  __builtin_amdgcn_global_load_lds(                                            \
      (const __attribute__((address_space(1))) void*)(gptr),                   \
      (__attribute__((address_space(3))) void*)(lptr), 16, 0, 0)

// counted vmcnt wait (never drain to 0 in steady state) + full scheduler fence
#define WAITV(N) do { asm volatile("s_waitcnt vmcnt(" #N ")" ::: "memory");    \
                      __builtin_amdgcn_sched_barrier(0); } while (0)

#define SBAR() __builtin_amdgcn_sched_barrier(0)
// selective fence: DS and VMEM issue order PINNED (vmcnt ledger + LDS-WAR
// safety identical to a full fence) but ALU/VALU/SALU/MFMA (mask 0xF) may
// cross -> adjacent phases' MFMA clusters overlap each other's latency.
#define SBARX() __builtin_amdgcn_sched_barrier(0x000F)

// ---------------------------------------------------------------------------
// 1) Weights -> f16. Wcat rows: [0,512)=Wk [512,1536)=Wv [1536,2048)=Wq
//    [2048,3072)=Wg. hi all; lo only k,v rows. Wo -> hi only.
// ---------------------------------------------------------------------------
__global__ __launch_bounds__(256) void wconv_kernel(
    const float* __restrict__ Wq, const float* __restrict__ Wk,
    const float* __restrict__ Wv, const float* __restrict__ Wg,
    const float* __restrict__ Wo,
    f16* __restrict__ WcatHi, f16* __restrict__ WcatLoKV, f16* __restrict__ WoHi) {
  int tid = blockIdx.x * 256 + threadIdx.x;
  int e8 = tid * 8;
  if (e8 < 3145728) {
    int row = e8 >> 10, col = e8 & 1023;
    const float* src;
    if (row < 512)       src = Wk + (size_t)row * 1024 + col;
    else if (row < 1536) src = Wv + (size_t)(row - 512) * 1024 + col;
    else if (row < 2048) src = Wq + (size_t)(row - 1536) * 1024 + col;
    else                 src = Wg + (size_t)(row - 2048) * 1024 + col;
    f16 thi[8] __attribute__((aligned(16)));
    f16 tlo[8] __attribute__((aligned(16)));
#pragma unroll
    for (int j = 0; j < 8; j++) {
      float x = src[j];
      f16 h = (f16)x;
      thi[j] = h;
      tlo[j] = (f16)(x - (float)h);
    }
    *(uint4*)&WcatHi[e8] = *(const uint4*)thi;
    if (row < 1536) *(uint4*)&WcatLoKV[e8] = *(const uint4*)tlo;
  } else {
    int idx = e8 - 3145728;
    f16 t[8] __attribute__((aligned(16)));
#pragma unroll
    for (int j = 0; j < 8; j++) t[j] = (f16)Wo[idx + j];
    *(uint4*)&WoHi[idx] = *(const uint4*)t;
  }
}

// ---------------------------------------------------------------------------
// 2) Causal depthwise conv1d (K=4) + SiLU -> x hi/lo, FUSED beta.
// ---------------------------------------------------------------------------
__global__ __launch_bounds__(256) void conv_kernel(
    const float* __restrict__ hs, const float* __restrict__ cw,
    const float* __restrict__ Wb,
    f16* __restrict__ xhi, f16* __restrict__ xlo, float* __restrict__ betaf) {
  int row = blockIdx.x;
  int b = row >> 11, l = row & 2047;
  int t = threadIdx.x;
  int d = t * 4;
  __shared__ floatx4 red[256];
  floatx4 w0 = *(const floatx4*)&cw[(d + 0) * 4];
  floatx4 w1 = *(const floatx4*)&cw[(d + 1) * 4];
  floatx4 w2 = *(const floatx4*)&cw[(d + 2) * 4];
  floatx4 w3 = *(const floatx4*)&cw[(d + 3) * 4];
  floatx4 acc = {0.f, 0.f, 0.f, 0.f};
#pragma unroll
  for (int j = 0; j < 4; j++) {
    int ls = l - 3 + j;
    if (ls < 0) continue;
    floatx4 hv = *(const floatx4*)&hs[(size_t)(b * 2048 + ls) * 1024 + d];
    acc[0] += hv[0] * w0[j];
    acc[1] += hv[1] * w1[j];
    acc[2] += hv[2] * w2[j];
    acc[3] += hv[3] * w3[j];
  }
  float yv[4];
  f16 ohi[4] __attribute__((aligned(8)));
  f16 olo[4] __attribute__((aligned(8)));
#pragma unroll
  for (int q = 0; q < 4; q++) {
    float y = acc[q] * sigmoidf_(acc[q]);
    yv[q] = y;
    f16 h = (f16)y;
    ohi[q] = h;
    olo[q] = (f16)(y - (float)h);
  }
  *(uint2*)&xhi[(size_t)row * 1024 + d] = *(const uint2*)ohi;
  *(uint2*)&xlo[(size_t)row * 1024 + d] = *(const uint2*)olo;
  // beta reduction (identical tree order to the old beta_kernel)
  floatx4 p = {0.f, 0.f, 0.f, 0.f};
#pragma unroll
  for (int hh = 0; hh < 4; hh++) {
    const float* wr = Wb + hh * 1024 + d;
    p[hh] = yv[0] * wr[0] + yv[1] * wr[1] + yv[2] * wr[2] + yv[3] * wr[3];
  }
  red[t] = p;
  __syncthreads();
  for (int s = 128; s > 0; s >>= 1) {
    if (t < s) red[t] += red[t + s];
    __syncthreads();
  }
  if (t < 4) betaf[(size_t)row * 4 + t] = sigmoidf_(red[0][t]);
}

// ---------------------------------------------------------------------------
// 4) MERGED x-projection GEMM, grid (24, 64).
// ---------------------------------------------------------------------------
__global__ __launch_bounds__(256) void gemm_qkvg(
    const f16* __restrict__ Ahi, const f16* __restrict__ Alo,
    const f16* __restrict__ Bhi, const f16* __restrict__ Blo,
    f16* __restrict__ ChHi, f16* __restrict__ ChLo) {
  const int K = 1024;
  __shared__ __attribute__((aligned(16))) f16 AsH[4096];
  __shared__ __attribute__((aligned(16))) f16 AsL[4096];
  __shared__ __attribute__((aligned(16))) f16 BsH[4096];
  __shared__ __attribute__((aligned(16))) f16 BsL[4096];
  const int t = threadIdx.x;
  const int lane = t & 63, wave = t >> 6;
  const int lc = lane & 15, quad = lane >> 4;
  const int wm = (wave >> 1) * 64, wn = (wave & 1) * 64;
  const int m0 = blockIdx.y * 128, n0 = blockIdx.x * 128;
  const bool hilo = (blockIdx.x < 12);     // k,v cols carry lo corrections
  const int scol = ((lane & 3) ^ ((lane >> 3) & 3)) * 8;
  int srow[2];
#pragma unroll
  for (int pp = 0; pp < 2; pp++) srow[pp] = (wave * 2 + pp) * 16 + (lane >> 2);
  const int swz = (quad ^ ((lc >> 1) & 3)) * 8;
  floatx4 acc[4][4] = {};
  for (int kt = 0; kt < K; kt += 32) {
    __syncthreads();
#pragma unroll
    for (int pp = 0; pp < 2; pp++) {
      int ldso = (wave * 2 + pp) * 512;
      GLOAD_LDS(&Ahi[(size_t)(m0 + srow[pp]) * K + kt + scol], AsH + ldso);
      GLOAD_LDS(&Bhi[(size_t)(n0 + srow[pp]) * K + kt + scol], BsH + ldso);
      if (hilo) {
        GLOAD_LDS(&Alo[(size_t)(m0 + srow[pp]) * K + kt + scol], AsL + ldso);
        GLOAD_LDS(&Blo[(size_t)(n0 + srow[pp]) * K + kt + scol], BsL + ldso);
      }
    }
    __syncthreads();    // drains vmcnt(0) -> staged data visible
    f16x8 ah[4], bh2[4];
#pragma unroll
    for (int i = 0; i < 4; i++) ah[i] = *(const f16x8*)&AsH[(wm + i * 16 + lc) * 32 + swz];
#pragma unroll
    for (int j = 0; j < 4; j++) bh2[j] = *(const f16x8*)&BsH[(wn + j * 16 + lc) * 32 + swz];
    if (hilo) {
      f16x8 al[4], bl[4];
#pragma unroll
      for (int i = 0; i < 4; i++) al[i] = *(const f16x8*)&AsL[(wm + i * 16 + lc) * 32 + swz];
#pragma unroll
      for (int j = 0; j < 4; j++) bl[j] = *(const f16x8*)&BsL[(wn + j * 16 + lc) * 32 + swz];
#pragma unroll
      for (int i = 0; i < 4; i++)
#pragma unroll
        for (int j = 0; j < 4; j++) {
          acc[i][j] = MFMA32(ah[i], bh2[j], acc[i][j]);
          acc[i][j] = MFMA32(al[i], bh2[j], acc[i][j]);
          acc[i][j] = MFMA32(ah[i], bl[j], acc[i][j]);
        }
    } else {
#pragma unroll
      for (int i = 0; i < 4; i++)
#pragma unroll
        for (int j = 0; j < 4; j++) acc[i][j] = MFMA32(ah[i], bh2[j], acc[i][j]);
    }
  }
#pragma unroll
  for (int i = 0; i < 4; i++)
#pragma unroll
    for (int j = 0; j < 4; j++)
#pragma unroll
      for (int rr = 0; rr < 4; rr++) {
        int row = m0 + wm + i * 16 + quad * 4 + rr;
        int col = n0 + wn + j * 16 + lc;
        float x = acc[i][j][rr];
        f16 h = (f16)x;
        ChHi[(size_t)row * 3072 + col] = h;
        if (hilo) ChLo[(size_t)row * 1536 + col] = (f16)(x - (float)h);
      }
}

// ---------------------------------------------------------------------------
// 4b) Plain f16 GEMM (global_load_lds staging) — output projection only.
// ---------------------------------------------------------------------------
template <int OUTF16>
__global__ __launch_bounds__(256) void gemm_plain(
    const f16* __restrict__ A, const f16* __restrict__ Bw,
    f16* __restrict__ Ch, float* __restrict__ Cf, int K, int ldc) {
  __shared__ __attribute__((aligned(16))) f16 As[4096];
  __shared__ __attribute__((aligned(16))) f16 Bs[4096];
  const int t = threadIdx.x;
  const int lane = t & 63, wave = t >> 6;
  const int lc = lane & 15, quad = lane >> 4;
  const int wm = (wave >> 1) * 64, wn = (wave & 1) * 64;
  const int m0 = blockIdx.y * 128, n0 = blockIdx.x * 128;
  const int scol = ((lane & 3) ^ ((lane >> 3) & 3)) * 8;
  int srow[2];
#pragma unroll
  for (int pp = 0; pp < 2; pp++) srow[pp] = (wave * 2 + pp) * 16 + (lane >> 2);
  const int swz = (quad ^ ((lc >> 1) & 3)) * 8;
  floatx4 acc[4][4] = {};
  for (int kt = 0; kt < K; kt += 32) {
    __syncthreads();
#pragma unroll
    for (int pp = 0; pp < 2; pp++) {
      int ldso = (wave * 2 + pp) * 512;
      GLOAD_LDS(&A[(size_t)(m0 + srow[pp]) * K + kt + scol],  As + ldso);
      GLOAD_LDS(&Bw[(size_t)(n0 + srow[pp]) * K + kt + scol], Bs + ldso);
    }
    __syncthreads();
    f16x8 af[4], bf[4];
#pragma unroll
    for (int i = 0; i < 4; i++) af[i] = *(const f16x8*)&As[(wm + i * 16 + lc) * 32 + swz];
#pragma unroll
    for (int j = 0; j < 4; j++) bf[j] = *(const f16x8*)&Bs[(wn + j * 16 + lc) * 32 + swz];
#pragma unroll
    for (int i = 0; i < 4; i++)
#pragma unroll
      for (int j = 0; j < 4; j++) acc[i][j] = MFMA32(af[i], bf[j], acc[i][j]);
  }
#pragma unroll
  for (int i = 0; i < 4; i++)
#pragma unroll
    for (int j = 0; j < 4; j++)
#pragma unroll
      for (int rr = 0; rr < 4; rr++) {
        int row = m0 + wm + i * 16 + quad * 4 + rr;
        int col = n0 + wn + j * 16 + lc;
        if (OUTF16) Ch[(size_t)row * ldc + col] = (f16)acc[i][j][rr];
        else        Cf[(size_t)row * ldc + col] = acc[i][j][rr];
      }
}

// ---------------------------------------------------------------------------
// 5) Chunk pre-pass (unchanged).
// ---------------------------------------------------------------------------
__global__ __launch_bounds__(256) void prepass_kernel(
    const f16* __restrict__ qkvgHi, const f16* __restrict__ kvLo,
    const float* __restrict__ betaf,
    f16* __restrict__ wHi, f16* __restrict__ wLo,
    f16* __restrict__ kTHi, f16* __restrict__ kTLo,
    f16* __restrict__ uHi, f16* __restrict__ uLo,
    float* __restrict__ attno) {
  int bid = blockIdx.x;          // 16*128
  int bh = bid >> 7, n = bid & 127;
  int b = bh >> 2, h = bh & 3;
  int t = threadIdx.x;

  __shared__ __attribute__((aligned(16))) float kc[16][132];
  __shared__ __attribute__((aligned(16))) float qc[16][132];
  __shared__ __attribute__((aligned(16))) float vb[16][260];
  __shared__ float Mm[16][16];
  __shared__ float Tt[16][16];
  __shared__ float Tb[16][16];
  __shared__ float part[16][16];
  __shared__ float betas[16];
  __shared__ float nrm[16];

  const size_t rowbase = (size_t)(b * 2048 + n * 16);
  {
    int i = t >> 4, o8 = (t & 15) * 8;
    size_t oh = (rowbase + i) * 3072;
    size_t ol = (rowbase + i) * 1536;
#pragma unroll
    for (int j = 0; j < 8; j++)
      kc[i][o8 + j] = (float)qkvgHi[oh + h * 128 + o8 + j] +
                      (float)kvLo[ol + h * 128 + o8 + j];
#pragma unroll
    for (int j = 0; j < 8; j++)
      qc[i][o8 + j] = (float)qkvgHi[oh + 1536 + h * 128 + o8 + j];
  }
  if (t < 16) betas[t] = betaf[(rowbase + t) * 4 + h];
  __syncthreads();
  {
    int i = t >> 4, sg = t & 15;
    float s = 0.f;
#pragma unroll
    for (int j = 0; j < 8; j++) { float v = kc[i][sg * 8 + j]; s += v * v; }
    part[i][sg] = s;
  }
  __syncthreads();
  if (t < 16) {
    float s = 0.f;
#pragma unroll
    for (int j = 0; j < 16; j++) s += part[t][j];
    nrm[t] = rsqrtf(s + 1e-12f);
  }
  __syncthreads();
  {
    int i = t >> 4, o8 = (t & 15) * 8;
    float sc = nrm[i];
#pragma unroll
    for (int j = 0; j < 8; j++) kc[i][o8 + j] *= sc;
  }
  __syncthreads();
  { // kT: normalized k transposed [d][token], hi/lo
    int d = t & 127, ih = t >> 7;
    f16 thi[8] __attribute__((aligned(16)));
    f16 tlo[8] __attribute__((aligned(16)));
#pragma unroll
    for (int j = 0; j < 8; j++) {
      float x = kc[ih * 8 + j][d];
      f16 hh = (f16)x;
      thi[j] = hh;
      tlo[j] = (f16)(x - (float)hh);
    }
    size_t base = ((size_t)bh * 128 + n) * 2048 + d * 16 + ih * 8;
    *(uint4*)&kTHi[base] = *(const uint4*)thi;
    *(uint4*)&kTLo[base] = *(const uint4*)tlo;
  }
  { // M = I + beta_i * (k_i . k_j) strictly-lower
    int i = t >> 4, j = t & 15;
    float s = 0.f;
    for (int x = 0; x < 128; x += 4)
      s += kc[i][x] * kc[j][x] + kc[i][x + 1] * kc[j][x + 1] +
           kc[i][x + 2] * kc[j][x + 2] + kc[i][x + 3] * kc[j][x + 3];
    Mm[i][j] = (i == j ? 1.f : 0.f) + ((j < i) ? betas[i] * s : 0.f);
  }
  __syncthreads();
  if (t < 16) { // forward substitution, column t of T = M^-1
    int j = t;
    float Tc[16];
#pragma unroll
    for (int i = 0; i < 16; i++) Tc[i] = 0.f;
    Tc[j] = 1.f;
    for (int i = j + 1; i < 16; i++) {
      float s = 0.f;
      for (int k2 = j; k2 < i; k2++) s += Mm[i][k2] * Tc[k2];
      Tc[i] = -s;
    }
    for (int i = 0; i < 16; i++) Tt[i][j] = Tc[i];
  }
  __syncthreads();
  { int i = t >> 4, m = t & 15; Tb[i][m] = Tt[i][m] * betas[m]; }
  { // vb = v * beta
    int m = t >> 4, c16 = (t & 15) * 16;
    size_t oh = (rowbase + m) * 3072 + 512 + h * 256 + c16;
    size_t ol = (rowbase + m) * 1536 + 512 + h * 256 + c16;
    float bm = betas[m];
#pragma unroll
    for (int j = 0; j < 16; j++)
      vb[m][c16 + j] = bm * ((float)qkvgHi[oh + j] + (float)kvLo[ol + j]);
  }
  __syncthreads();
  { // -w = -(Tb @ k_norm), hi/lo
    int i = t >> 4, dg = t & 15;
    f16 thi[8] __attribute__((aligned(16)));
    f16 tlo[8] __attribute__((aligned(16)));
#pragma unroll
    for (int dd = 0; dd < 8; dd++) {
      int d = dg * 8 + dd;
      float s = 0.f;
#pragma unroll
      for (int m = 0; m < 16; m++) s += Tb[i][m] * kc[m][d];
      s = -s;
      f16 hh = (f16)s;
      thi[dd] = hh;
      tlo[dd] = (f16)(s - (float)hh);
    }
    size_t base = ((size_t)bh * 128 + n) * 2048 + i * 128 + dg * 8;
    *(uint4*)&wHi[base] = *(const uint4*)thi;
    *(uint4*)&wLo[base] = *(const uint4*)tlo;
  }
  { // u = Tt @ vb, hi/lo, chunk-TRANSPOSED out: [vg][bh][n][vv][i]
    int v = t;
    f16 thi[16] __attribute__((aligned(16)));
    f16 tlo[16] __attribute__((aligned(16)));
#pragma unroll
    for (int i = 0; i < 16; i++) {
      float s2 = 0.f;
#pragma unroll
      for (int m = 0; m < 16; m++) s2 += Tt[i][m] * vb[m][v];
      f16 hh = (f16)s2;
      thi[i] = hh;
      tlo[i] = (f16)(s2 - (float)hh);
    }
    size_t base = ((((size_t)(v >> 4) * 16 + bh) * 128 + n) * 16 + (v & 15)) * 16;
    ((uint4*)&uHi[base])[0] = ((const uint4*)thi)[0];
    ((uint4*)&uHi[base])[1] = ((const uint4*)thi)[1];
    ((uint4*)&uLo[base])[0] = ((const uint4*)tlo)[0];
    ((uint4*)&uLo[base])[1] = ((const uint4*)tlo)[1];
  }
  { // attn = qscale * (q . k_norm), causal inclusive, fp32
    int i = t >> 4, j = t & 15;
    float s = 0.f;
    for (int x = 0; x < 128; x++) s += qc[i][x] * kc[j][x];
    attno[((size_t)bh * 128 + n) * 256 + i * 16 + j] = (j <= i) ? QSCALE * s : 0.f;
  }
}

// ---------------------------------------------------------------------------
// 5b) Pair-coupling pre-pass (unchanged): CAB = (-wB)@kTA, DBA = qB@kTA,
//     stored in qkvgHi's dead v-region (row bh*64+sc, col 512+...).
// ---------------------------------------------------------------------------
__global__ __launch_bounds__(256) void cabd_kernel(
    f16* qkvg,
    const f16* __restrict__ wHi, const f16* __restrict__ wLo,
    const f16* __restrict__ kTHi, const f16* __restrict__ kTLo) {
  int bid = blockIdx.x;            // 16*64
  int bh = bid >> 6, sc = bid & 63;
  int b = bh >> 2, h = bh & 3;
  int t = threadIdx.x;
  int cA = 2 * sc, cB = 2 * sc + 1;
  const size_t cb = (size_t)bh * 128;

  __shared__ float wf[16][128];
  __shared__ float qf[16][128];
  __shared__ float kf[128][17];

  {
    int i = t >> 4, d0 = (t & 15) * 8;
    size_t wbase = (cb + cB) * 2048 + i * 128 + d0;
    size_t qbase = ((size_t)b * 2048 + cB * 16 + i) * 3072 + 1536 + h * 128 + d0;
#pragma unroll
    for (int j = 0; j < 8; j++) {
      wf[i][d0 + j] = (float)wHi[wbase + j] + (float)wLo[wbase + j];
      qf[i][d0 + j] = (float)qkvg[qbase + j];
    }
    int d = t >> 1, tk0 = (t & 1) * 8;
    size_t kb = (cb + cA) * 2048 + d * 16 + tk0;
#pragma unroll
    for (int j = 0; j < 8; j++)
      kf[d][tk0 + j] = (float)kTHi[kb + j] + (float)kTLo[kb + j];
  }
  __syncthreads();
  int i = t >> 4, j = t & 15;
  float sc1 = 0.f, sd1 = 0.f;
  for (int d = 0; d < 128; d++) {
    float kv = kf[d][j];
    sc1 += wf[i][d] * kv;
    sd1 += qf[i][d] * kv;
  }
  f16 ch = (f16)sc1, dh = (f16)sd1;
  size_t o = (size_t)(bh * 64 + sc) * 3072 + 512 + i * 16 + j;
  qkvg[o]       = ch;  qkvg[o + 256] = (f16)(sc1 - (float)ch);
  qkvg[o + 512] = dh;  qkvg[o + 768] = (f16)(sd1 - (float)dh);
}

// ---------------------------------------------------------------------------
// 6) Delta-rule scan, SUPERCHUNK-2 — R7/R10 body with SELECTIVE scheduler
//    fences: in-body sched_barrier(0) -> sched_barrier(0xF) (DS/VMEM issue
//    order pinned = identical vmcnt ledger + LDS-WAR safety; ALU/VALU/MFMA
//    may cross -> phase MFMA clusters fill each other's latency shadows).
//    WAITV keeps the full fence.  o stored f16, unified buffer.
//    vmcnt ledger (groups): B16 U4 W16 stA4 stB4 K16 = 60/body.
//      top WAITV(16); mid WAITV(44) (sc==63: 24); peaks <= 60 <= 63.
// ---------------------------------------------------------------------------
#define STG_W   0
#define STG_WL  2048
#define STG_KH  4096
#define STG_KL  6144
#define STG_CH  8192     // f16 per chunk buffer (16KB)

__global__ __launch_bounds__(64, 1) void scan_kernel(
    const f16* __restrict__ qkvgHi,
    const f16* __restrict__ wHi, const f16* __restrict__ wLo,
    const f16* __restrict__ kTHi, const f16* __restrict__ kTLo,
    const float* __restrict__ attn,
    const f16* __restrict__ uHi, const f16* __restrict__ uLo,
    f16* __restrict__ of) {
  const int bid = blockIdx.x;
  const int slc = bid >> 4, bh = bid & 15;   // XCD-local: bid%8 = bh%8
  const int b = bh >> 2, h = bh & 3;
  const int v0 = slc * 16;
  const int lane = threadIdx.x;
  const int lc = lane & 15, quad = lane >> 4;
  const int qh = quad & 1;

  __shared__ __attribute__((aligned(16))) f16 stg[2][STG_CH];  // [chunk-in-pair]
  __shared__ __attribute__((aligned(16))) f16 S_hi[16][136];
  __shared__ __attribute__((aligned(16))) f16 S_lo[16][136];

  floatx4 accS[8] = {};   // S[dt*16 + quad*4 + r][v0 + lc]

  const size_t cb = (size_t)bh * 128;
  const f16* qb = qkvgHi + (size_t)b * 2048 * 3072 + 1536 + h * 128;
  const f16* ubH = uHi + ((size_t)(slc * 16 + bh)) * 32768 + lc * 16 + quad * 4;
  const f16* ubL = uLo + ((size_t)(slc * 16 + bh)) * 32768 + lc * 16 + quad * 4;
  const float* ab = attn + cb * 256 + lc * 16 + qh * 8;
  // CAB/DBA tables in qkvgHi v-region: row bh*64+sc, col 512+...
  const f16* cd = qkvgHi + (size_t)(bh * 64) * 3072 + 512 + lc * 16 + qh * 8;
  f16* ob = of + (size_t)bh * 2048 * 256;

  // per-lane swizzled source offsets (chunk-invariant)
  int woff[4], koff[4];
#pragma unroll
  for (int p = 0; p < 4; p++) {
    int cid = p * 64 + lane;
    int row = cid >> 4, dgs = (cid & 15) ^ (row & 7);
    int d = cid >> 1,  ih = (cid & 1) ^ ((cid >> 3) & 1);
    woff[p] = row * 128 + dgs * 8;
    koff[p] = d * 16 + ih * 8;
  }

  // u prefetch, 2 slots (the only cross-body register prefetch)
  uint2 puhA[2], pulA[2], puhB[2], pulB[2];

  auto ISSUE_U = [&](int slot, int sc) {   // 4 VMEM
    puhA[slot] = *(const uint2*)(ubH + (size_t)(2 * sc) * 256);
    pulA[slot] = *(const uint2*)(ubL + (size_t)(2 * sc) * 256);
    puhB[slot] = *(const uint2*)(ubH + (size_t)(2 * sc + 1) * 256);
    pulB[slot] = *(const uint2*)(ubL + (size_t)(2 * sc + 1) * 256);
  };
  auto ISSUE_W = [&](int sc) {   // 16 gloads (both chunks)
#pragma unroll
    for (int ci = 0; ci < 2; ci++) {
      const f16* ws = wHi + (cb + (size_t)(2 * sc + ci)) * 2048;
      const f16* wl = wLo + (cb + (size_t)(2 * sc + ci)) * 2048;
      f16* sbp = &stg[ci][0];
#pragma unroll
      for (int p = 0; p < 4; p++) {
        GLOAD_LDS(ws + woff[p], sbp + STG_W  + p * 512);
        GLOAD_LDS(wl + woff[p], sbp + STG_WL + p * 512);
      }
    }
  };
  auto ISSUE_K = [&](int sc) {   // 16 gloads (both chunks)
#pragma unroll
    for (int ci = 0; ci < 2; ci++) {
      const f16* kh = kTHi + (cb + (size_t)(2 * sc + ci)) * 2048;
      const f16* kl = kTLo + (cb + (size_t)(2 * sc + ci)) * 2048;
      f16* sbp = &stg[ci][0];
#pragma unroll
      for (int p = 0; p < 4; p++) {
        GLOAD_LDS(kh + koff[p], sbp + STG_KH + p * 512);
        GLOAD_LDS(kl + koff[p], sbp + STG_KL + p * 512);
      }
    }
  };

  auto SHFL_EXCH = [&](floatx4 acc_u) -> f16x8 {
    f16 h0 = (f16)acc_u[0], h1 = (f16)acc_u[1];
    f16 h2 = (f16)acc_u[2], h3 = (f16)acc_u[3];
    uint32_t uh01 = pack2(h0, h1), uh23 = pack2(h2, h3);
    uint32_t ul01 = pack2((f16)(acc_u[0] - (float)h0), (f16)(acc_u[1] - (float)h1));
    uint32_t ul23 = pack2((f16)(acc_u[2] - (float)h2), (f16)(acc_u[3] - (float)h3));
    int srcA = (2 * qh) * 16 + lc;
    int srcB = srcA + 16;
    uint32_t Ah0 = __shfl((int)uh01, srcA, 64), Ah1 = __shfl((int)uh23, srcA, 64);
    uint32_t Bh0 = __shfl((int)uh01, srcB, 64), Bh1 = __shfl((int)uh23, srcB, 64);
    uint32_t Al0 = __shfl((int)ul01, srcA, 64), Al1 = __shfl((int)ul23, srcA, 64);
    uint32_t Bl0 = __shfl((int)ul01, srcB, 64), Bl1 = __shfl((int)ul23, srcB, 64);
    union { uint32_t u[4]; f16x8 v; } U;
    bool hi = (quad < 2);
    U.u[0] = hi ? Ah0 : Al0;
    U.u[1] = hi ? Ah1 : Al1;
    U.u[2] = hi ? Bh0 : Bl0;
    U.u[3] = hi ? Bh1 : Bl1;
    return U.v;
  };

  // attn fp32x8 -> hi/lo f16x8 frags
  auto ATTN_SPLIT = [&](uint4 p0, uint4 p1, f16x8& hh, f16x8& ll) {
    union { uint4 u4[2]; float f[8]; } PA;
    PA.u4[0] = p0; PA.u4[1] = p1;
#pragma unroll
    for (int j = 0; j < 8; j++) {
      float a = PA.f[j];
      f16 ah = (f16)a;
      hh[j] = ah;
      ll[j] = (f16)(a - (float)ah);
    }
  };

  const int kswz = (qh ^ ((lc >> 2) & 1)) * 8 + lc * 16;

  // prologue: superchunk 0 fully in flight (U4 + W16 + K16 = 36)
  ISSUE_U(0, 0); SBAR();
  ISSUE_W(0);    SBAR();
  ISSUE_K(0);    SBAR();

  for (int s2 = 0; s2 < NSUPER; s2 += 2) {
#pragma unroll
    for (int half = 0; half < 2; half++) {
      const int sc = s2 + half;
      const int slot = half;           // = sc & 1
      const int cA = 2 * sc;

      // ---- 1. dump S (state after superchunk sc-1) hi/lo to LDS
#pragma unroll
      for (int dt = 0; dt < 8; dt++) {
        f16x4 h4, l4;
#pragma unroll
        for (int r = 0; r < 4; r++) {
          float x = accS[dt][r];
          f16 hh = (f16)x;
          h4[r] = hh;
          l4[r] = (f16)(x - (float)hh);
        }
        *(f16x4*)&S_hi[lc][dt * 16 + quad * 4] = h4;
        *(f16x4*)&S_lo[lc][dt * 16 + quad * 4] = l4;
      }

      // ---- 2. top wait: W(sc)+U(sc) staged (16 = K(sc) left outstanding)
      WAITV(16);

      // ---- 3. same-body register loads: attn, CAB/DBA, q (B group, 16)
      uint4 paA0 = *(const uint4*)(ab + (size_t)cA * 256);
      uint4 paA1 = *(const uint4*)(ab + (size_t)cA * 256 + 4);
      uint4 paB0 = *(const uint4*)(ab + (size_t)(cA + 1) * 256);
      uint4 paB1 = *(const uint4*)(ab + (size_t)(cA + 1) * 256 + 4);
      const f16* cdp = cd + (size_t)sc * 3072;
      f16x8 cabh = *(const f16x8*)(cdp);
      f16x8 cabl = *(const f16x8*)(cdp + 256);
      f16x8 dbah = *(const f16x8*)(cdp + 512);
      f16x8 dbal = *(const f16x8*)(cdp + 768);
      f16x8 qfA[4], qfB[4];
#pragma unroll
      for (int ks = 0; ks < 4; ks++) {
        qfA[ks] = *(const f16x8*)(qb + (size_t)(cA * 16 + lc) * 3072 + ks * 32 + quad * 8);
        qfB[ks] = *(const f16x8*)(qb + (size_t)((cA + 1) * 16 + lc) * 3072 + ks * 32 + quad * 8);
      }
      SBARX();

      // ---- 4. consume u prefetch
      floatx4 acc_uA, acc_uB;
      {
        union { uint2 u2; f16 hh[4]; } Uh, Ul;
        Uh.u2 = puhA[slot]; Ul.u2 = pulA[slot];
#pragma unroll
        for (int r = 0; r < 4; r++) acc_uA[r] = (float)Uh.hh[r] + (float)Ul.hh[r];
        Uh.u2 = puhB[slot]; Ul.u2 = pulB[slot];
#pragma unroll
        for (int r = 0; r < 4; r++) acc_uB[r] = (float)Uh.hh[r] + (float)Ul.hh[r];
      }
      // ---- 5. next-superchunk u prefetch (U group, 4)
      if (sc + 1 < NSUPER) ISSUE_U(slot ^ 1, sc + 1);
      SBARX();

      // ---- 6. S frags + wA frags
      f16x8 shf[4], slf[4], wah[4], wal[4];
      f16* sbA = &stg[0][0];
      f16* sbB = &stg[1][0];
#pragma unroll
      for (int ks = 0; ks < 4; ks++) {
        shf[ks] = *(const f16x8*)&S_hi[lc][ks * 32 + quad * 8];
        slf[ks] = *(const f16x8*)&S_lo[lc][ks * 32 + quad * 8];
        int gi = lc * 128 + (((ks * 4 + quad) ^ (lc & 7)) * 8);
        wah[ks] = *(const f16x8*)(sbA + STG_W  + gi);
        wal[ks] = *(const f16x8*)(sbA + STG_WL + gi);
      }
      // ---- 7. yA trio (bit-identical A path)
      floatx4 a1 = {0.f,0.f,0.f,0.f}, a2 = {0.f,0.f,0.f,0.f};
#pragma unroll
      for (int ks = 0; ks < 4; ks++) {
        acc_uA = MFMA32(wah[ks], shf[ks], acc_uA);
        a1     = MFMA32(wah[ks], slf[ks], a1);
        a2     = MFMA32(wal[ks], shf[ks], a2);
      }
      acc_uA = acc_uA + a1 + a2;

      // ---- 8. wB frags
      f16x8 wbh[4], wbl[4];
#pragma unroll
      for (int ks = 0; ks < 4; ks++) {
        int gi = lc * 128 + (((ks * 4 + quad) ^ (lc & 7)) * 8);
        wbh[ks] = *(const f16x8*)(sbB + STG_W  + gi);
        wbl[ks] = *(const f16x8*)(sbB + STG_WL + gi);
      }
      // ---- 9. yB trio
      floatx4 b1 = {0.f,0.f,0.f,0.f}, b2 = {0.f,0.f,0.f,0.f};
#pragma unroll
      for (int ks = 0; ks < 4; ks++) {
        acc_uB = MFMA32(wbh[ks], shf[ks], acc_uB);
        b1     = MFMA32(wbh[ks], slf[ks], b1);
        b2     = MFMA32(wbl[ks], slf[ks], b2);
      }
      // NOTE: keep exact R10 math — b2 uses wbl x shf (hi S), not slf:
      b2 = b2 - b2;   // (recomputed below correctly; placeholder removed)
#pragma unroll
      for (int ks = 0; ks < 4; ks++) b2 = MFMA32(wbl[ks], shf[ks], b2);
      acc_uB = acc_uB + b1 + b2;
      SBARX();
      // ---- 10. W staging for sc+1 (w frag reads retired above) (W group, 16)
      if (sc + 1 < NSUPER) ISSUE_W(sc + 1);
      SBARX();

      // ---- 11. oA' = qA@S, oB' = qB@S (parallel filler)
      floatx4 acc_oA = {0.f,0.f,0.f,0.f}, acc_oB = {0.f,0.f,0.f,0.f};
#pragma unroll
      for (int ks = 0; ks < 4; ks++) {
        acc_oA = MFMA32(qfA[ks], shf[ks], acc_oA);
        acc_oB = MFMA32(qfB[ks], shf[ks], acc_oB);
      }
#pragma unroll
      for (int ks = 0; ks < 4; ks++) {
        acc_oA = MFMA32(qfA[ks], slf[ks], acc_oA);
        acc_oB = MFMA32(qfB[ks], slf[ks], acc_oB);
      }

      // ---- 12. exchange A
      f16x8 ubfA = SHFL_EXCH(acc_uA);

      // ---- 13. couple B to A: u_adjB += CAB@u_adjA; oB' += DBA@u_adjA
      acc_uB = MFMA32(cabh, ubfA, acc_uB);
      acc_uB = MFMA32(cabl, ubfA, acc_uB);
      acc_oB = MFMA32(dbah, ubfA, acc_oB);
      acc_oB = MFMA32(dbal, ubfA, acc_oB);

      // ---- 14. finish oA (bit-identical A path) + store f16 (stA group, 4)
      {
        f16x8 aah, aal;
        ATTN_SPLIT(paA0, paA1, aah, aal);
#pragma unroll
        for (int r = 0; r < 4; r++) acc_oA[r] *= QSCALE;
        acc_oA = MFMA32(aah, ubfA, acc_oA);
        acc_oA = MFMA32(aal, ubfA, acc_oA);
      }
#pragma unroll
      for (int r = 0; r < 4; r++)
        ob[(size_t)(cA * 16 + quad * 4 + r) * 256 + v0 + lc] = (f16)acc_oA[r];
      SBARX();

      // ---- 15. exchange B, finish oB + store f16 (stB group, 4)
      f16x8 ubfB = SHFL_EXCH(acc_uB);
      {
        f16x8 bah, bal;
        ATTN_SPLIT(paB0, paB1, bah, bal);
#pragma unroll
        for (int r = 0; r < 4; r++) acc_oB[r] *= QSCALE;
        acc_oB = MFMA32(bah, ubfB, acc_oB);
        acc_oB = MFMA32(bal, ubfB, acc_oB);
      }
#pragma unroll
      for (int r = 0; r < 4; r++)
        ob[(size_t)((cA + 1) * 16 + quad * 4 + r) * 256 + v0 + lc] = (f16)acc_oB[r];
      SBARX();

      // ---- 16. mid wait: K(sc) staged.  Newer: B16+U4+W16+stA4+stB4 = 44
      if (sc + 1 < NSUPER) { WAITV(44); } else { WAITV(24); }

      // ---- 17. S += kTA@u_adjA + kTB@u_adjB
#pragma unroll
      for (int dt = 0; dt < 8; dt++) {
        f16x8 kah = *(const f16x8*)(sbA + STG_KH + dt * 256 + kswz);
        f16x8 kal = *(const f16x8*)(sbA + STG_KL + dt * 256 + kswz);
        accS[dt] = MFMA32(kah, ubfA, accS[dt]);
        accS[dt] = MFMA32(kal, ubfA, accS[dt]);
      }
#pragma unroll
      for (int dt = 0; dt < 8; dt++) {
        f16x8 kbh = *(const f16x8*)(sbB + STG_KH + dt * 256 + kswz);
        f16x8 kbl = *(const f16x8*)(sbB + STG_KL + dt * 256 + kswz);
        accS[dt] = MFMA32(kbh, ubfB, accS[dt]);
        accS[dt] = MFMA32(kbl, ubfB, accS[dt]);
      }
      SBARX();
      // ---- 18. K staging for sc+1 (kT frag reads retired above) (K group, 16)
      if (sc + 1 < NSUPER) ISSUE_K(sc + 1);
      SBARX();
    }
  }
}

// ---------------------------------------------------------------------------
// 7) Gated RMSNorm -> on f16 (o f16, unified bh-major buffer)
// ---------------------------------------------------------------------------
__global__ __launch_bounds__(256) void gate_kernel(
    const f16* __restrict__ of,
    const f16* __restrict__ qkvgHi, const float* __restrict__ norm_w,
    f16* __restrict__ onh) {
  int h = threadIdx.x >> 6, lane = threadIdx.x & 63;
  int r = blockIdx.x;              // b*L + l
  int b = r >> 11, l = r & 2047;
  int bh = b * 4 + h;
  const f16* orow = of + ((size_t)bh * 2048 + l) * 256;
  int v = lane * 4;
  float ov[4];
  {
    union { uint2 u2; f16 hh[4]; } O;
    O.u2 = *(const uint2*)&orow[v];
#pragma unroll
    for (int j = 0; j < 4; j++) ov[j] = (float)O.hh[j];
  }
  float ss = ov[0] * ov[0] + ov[1] * ov[1] + ov[2] * ov[2] + ov[3] * ov[3];
  for (int m = 32; m > 0; m >>= 1) ss += __shfl_xor(ss, m);
  float rms = rsqrtf(ss * (1.0f / 256.0f) + 1e-5f);
  size_t goff = (size_t)r * 3072 + 2048 + h * 256 + v;
  floatx4 nw = *(const floatx4*)&norm_w[v];
  f16 outv[4] __attribute__((aligned(8)));
#pragma unroll
  for (int q2 = 0; q2 < 4; q2++) {
    float g = (float)qkvgHi[goff + q2];
    outv[q2] = (f16)(ov[q2] * rms * nw[q2] * (g * sigmoidf_(g)));
  }
  *(uint2*)&onh[(size_t)r * 1024 + h * 256 + v] = *(const uint2*)outv;
}

// ---------------------------------------------------------------------------
extern "C" void kernel_launch(void* const* d_in, const int* in_sizes, int n_in,
                              void* d_out, int out_size, void* d_ws, size_t ws_size,
                              hipStream_t stream) {
  (void)in_sizes; (void)n_in; (void)out_size; (void)ws_size;
  const float* hs     = (const float*)d_in[0];
  const float* conv_w = (const float*)d_in[1];
  const float* Wq     = (const float*)d_in[2];
  const float* Wk     = (const float*)d_in[3];
  const float* Wv     = (const float*)d_in[4];
  const float* Wb     = (const float*)d_in[5];
  const float* Wg     = (const float*)d_in[6];
  const float* Wo     = (const float*)d_in[7];
  const float* norm_w = (const float*)d_in[8];
  float* out = (float*)d_out;

  char* ws = (char*)d_ws;
  f16*   x_hi    = (f16*)(ws + 0);            // 16,777,216  -> uHi after GEMM
  f16*   x_lo    = (f16*)(ws + 16777216);     // 16,777,216  -> uLo after GEMM
  f16*   uHi     = (f16*)(ws + 0);
  f16*   uLo     = (f16*)(ws + 16777216);
  f16*   WcatHi  = (f16*)(ws + 33554432);     //  6,291,456
  f16*   WcatLo  = (f16*)(ws + 39845888);     //  3,145,728  (kv rows only)
  f16*   WoHi    = (f16*)(ws + 42991616);     //  2,097,152
  float* betaf   = (float*)(ws + 45088768);   //    131,072
  f16*   qkvgHi  = (f16*)(ws + 45219840);     // 50,331,648  [8192][3072]
                                              //  (v-cols of rows 0..1023 hold
                                              //   CAB/DBA after cabd_kernel)
  f16*   kvLo    = (f16*)(ws + 95551488);     // 25,165,824  -> of16 after
  f16*   of16    = (f16*)(ws + 95551488);     // 16,777,216  [16][2048][256] f16
  f16*   wHi     = (f16*)(ws + 120717312);    //  8,388,608  -> on_h after scan
  f16*   on_h    = (f16*)(ws + 120717312);    // 16,777,216
  f16*   wLo     = (f16*)(ws + 129105920);    //  8,388,608
  f16*   kTHi    = (f16*)(ws + 137494528);    //  8,388,608
  f16*   kTLo    = (f16*)(ws + 145883136);    //  8,388,608
  float* attnf   = (float*)(ws + 154271744);  //  2,097,152  -> total 156,368,896

  wconv_kernel<<<2048, 256, 0, stream>>>(Wq, Wk, Wv, Wg, Wo, WcatHi, WcatLo, WoHi);
  conv_kernel<<<ROWS, 256, 0, stream>>>(hs, conv_w, Wb, x_hi, x_lo, betaf);
  gemm_qkvg<<<dim3(24, 64), 256, 0, stream>>>(
      x_hi, x_lo, WcatHi, WcatLo, qkvgHi, kvLo);
  prepass_kernel<<<16 * NCHUNK, 256, 0, stream>>>(
      qkvgHi, kvLo, betaf, wHi, wLo, kTHi, kTLo, uHi, uLo, attnf);
  cabd_kernel<<<16 * NSUPER, 256, 0, stream>>>(
      qkvgHi, wHi, wLo, kTHi, kTLo);
  scan_kernel<<<256, 64, 0, stream>>>(
      qkvgHi, wHi, wLo, kTHi, kTLo, attnf, uHi, uLo, of16);
  gate_kernel<<<ROWS, 256, 0, stream>>>(of16, qkvgHi, norm_w, on_h);
  gemm_plain<0><<<dim3(8, 64), 256, 0, stream>>>(
      on_h, WoHi, nullptr, out, 1024, 1024);
}